// Round 14
// baseline (209.692 us; speedup 1.0000x reference)
//
#include <hip/hip_runtime.h>

// SelfAttentionHead: B=4, T=4096, C=1024, H=64, causal, f32 in/out.
// prep_w -> qkv_proj (LDS dbuf MFMA GEMM; Q pre-scaled; V written DIRECTLY
// in key-permuted VT layout) -> attn (LDS-staged K/V dbuf, swapped QK^T,
// fixed-base softmax, 32 q-rows/wave, 8-way KV split, FUSED last-block
// merge via device-scope semaphore -- no separate merge kernel).

typedef short  s16x8 __attribute__((ext_vector_type(8)));
typedef float  f32x4 __attribute__((ext_vector_type(4)));
typedef unsigned u32x2 __attribute__((ext_vector_type(2)));

constexpr int B = 4, T = 4096, C = 1024, H = 64;
constexpr int M = B * T;                    // 16384 tokens
constexpr float LOG2E = 1.44269504088896340736f;
constexpr float QSCALE = 0.125f * LOG2E;    // H^-0.5 * log2(e): s in log2 domain
constexpr float MBASE  = 4.0f * LOG2E;      // fixed softmax base (nat-log 4)

__device__ __forceinline__ unsigned short f2bf(float f) {
    union { float f; unsigned u; } v; v.f = f;
    unsigned r = v.u + 0x7fffu + ((v.u >> 16) & 1u);   // RNE
    return (unsigned short)(r >> 16);
}

__device__ __forceinline__ unsigned cvt_pk_bf16(float lo, float hi) {
    unsigned r;
    asm("v_cvt_pk_bf16_f32 %0, %1, %2" : "=v"(r) : "v"(lo), "v"(hi));
    return r;   // [15:0]=bf16(lo), [31:16]=bf16(hi)
}

__device__ __forceinline__ void gl_lds16(const void* g, void* l) {
    __builtin_amdgcn_global_load_lds(
        (const __attribute__((address_space(1))) unsigned*)g,
        (__attribute__((address_space(3))) unsigned*)l, 16, 0, 0);
}

// ---------------------------------------------------------------------------
// Kernel 1: Wt[n][k] = W_{n/64}[k][n%64] as bf16.
// ---------------------------------------------------------------------------
__global__ void prep_w(const float* __restrict__ Wq, const float* __restrict__ Wk,
                       const float* __restrict__ Wv, unsigned short* __restrict__ Wt) {
    const int n = blockIdx.x;                       // 0..191
    const float* W = (n < 64) ? Wq : (n < 128 ? Wk : Wv);
    const int col = n & 63;
    for (int k = threadIdx.x; k < C; k += blockDim.x)
        Wt[(size_t)n * C + k] = f2bf(W[(size_t)k * H + col]);
}

// ---------------------------------------------------------------------------
// Kernel 2: fused QKV projection.  M=16384,K=1024,N=192 bf16 MFMA.
// 512 blocks x 512 thr (8 waves) share one BM=32 x BN=192 x BK=64
// double-buffered LDS tile.  B staged with global_load_lds (linear dest,
// pre-swizzled source); A reg-staged f32->bf16.  Q pre-scaled by QSCALE.
// V written directly into key-permuted transposed layout VT[b][h][pos].
// ---------------------------------------------------------------------------
__global__ __launch_bounds__(512) void qkv_proj(
    const float* __restrict__ x, const unsigned short* __restrict__ Wt,
    unsigned short* __restrict__ Q, unsigned short* __restrict__ K,
    unsigned short* __restrict__ VT) {
    __shared__ __align__(16) unsigned short ldsA[2][32 * 64];    //  8 KB
    __shared__ __align__(16) unsigned short ldsB[2][192 * 64];   // 48 KB

    const int t = threadIdx.x, lane = t & 63, w = t >> 6;
    const int i = lane & 15, g = lane >> 4;
    const int rowbase = blockIdx.x * 32;
    const int rw = w & 1, nw = w >> 1;              // row-group, N-quarter

    const int arow = t >> 3, aslot = t & 7;
    const float* aga = x + (size_t)(rowbase + arow) * C + ((aslot ^ (arow & 7)) * 8);
    const int awoff = arow * 64 + aslot * 8;
    const bool astage = (t < 256);

    const int brow8 = lane >> 3, bslot = lane & 7;
    const unsigned short* bga[3];
    int bn0[3];
#pragma unroll
    for (int j = 0; j < 3; ++j) {
        bn0[j] = w * 24 + j * 8;
        bga[j] = Wt + (size_t)(bn0[j] + brow8) * C + ((bslot ^ brow8) * 8);
    }

    f32x4 acc[3];
#pragma unroll
    for (int n = 0; n < 3; ++n) acc[n] = (f32x4){0.f, 0.f, 0.f, 0.f};

    {
#pragma unroll
        for (int j = 0; j < 3; ++j)
            gl_lds16(bga[j], &ldsB[0][bn0[j] * 64]);
        if (astage) {
            f32x4 a0 = *(const f32x4*)(aga);
            f32x4 a1 = *(const f32x4*)(aga + 4);
            union { unsigned u[4]; s16x8 v; } av;
            av.u[0] = cvt_pk_bf16(a0[0], a0[1]);
            av.u[1] = cvt_pk_bf16(a0[2], a0[3]);
            av.u[2] = cvt_pk_bf16(a1[0], a1[1]);
            av.u[3] = cvt_pk_bf16(a1[2], a1[3]);
            *(s16x8*)&ldsA[0][awoff] = av.v;
        }
    }
    __syncthreads();

    for (int it = 0; it < 16; ++it) {
        const int cur = it & 1, nxt = cur ^ 1;
        const int kc = (it + 1) * 64;
        f32x4 a0, a1;
        const bool more = (it < 15);
        if (more) {
            if (astage) {
                a0 = *(const f32x4*)(aga + kc);
                a1 = *(const f32x4*)(aga + kc + 4);
            }
#pragma unroll
            for (int j = 0; j < 3; ++j)
                gl_lds16(bga[j] + kc, &ldsB[nxt][bn0[j] * 64]);
        }
#pragma unroll
        for (int kst = 0; kst < 2; ++kst) {
            const int c = kst * 4 + g;
            s16x8 a = *(const s16x8*)&ldsA[cur][(rw * 16 + i) * 64 + ((c ^ (i & 7)) * 8)];
#pragma unroll
            for (int nt = 0; nt < 3; ++nt) {
                int n = nw * 48 + nt * 16 + i;        // n&7 == i&7
                s16x8 b = *(const s16x8*)&ldsB[cur][n * 64 + ((c ^ (i & 7)) * 8)];
                acc[nt] = __builtin_amdgcn_mfma_f32_16x16x32_bf16(a, b, acc[nt], 0, 0, 0);
            }
        }
        if (more && astage) {
            union { unsigned u[4]; s16x8 v; } av;
            av.u[0] = cvt_pk_bf16(a0[0], a0[1]);
            av.u[1] = cvt_pk_bf16(a0[2], a0[3]);
            av.u[2] = cvt_pk_bf16(a1[0], a1[1]);
            av.u[3] = cvt_pk_bf16(a1[2], a1[3]);
            *(s16x8*)&ldsA[nxt][awoff] = av.v;
        }
        __syncthreads();
    }

    // epilogue: D layout col=lane&15, row=4*(lane>>4)+r; per-nt region uniform
#pragma unroll
    for (int nt = 0; nt < 3; ++nt) {
        const int base = nw * 48 + nt * 16;
        const int n = base + i;
        if (base >= 128) {          // V -> direct key-permuted VT store
            const int h = n - 128;
            const int bb = rowbase >> 12, tb = rowbase & 4095;
            u32x2 pk;
            pk[0] = cvt_pk_bf16(acc[nt][0], acc[nt][1]);
            pk[1] = cvt_pk_bf16(acc[nt][2], acc[nt][3]);
            *(u32x2*)(VT + (size_t)(bb * H + h) * T + tb + g * 8 + rw * 4) = pk;
        } else if (base >= 64) {    // K
#pragma unroll
            for (int r = 0; r < 4; ++r)
                K[(size_t)(rowbase + rw * 16 + g * 4 + r) * H + (n - 64)] = f2bf(acc[nt][r]);
        } else {                    // Q (pre-scaled)
#pragma unroll
            for (int r = 0; r < 4; ++r)
                Q[(size_t)(rowbase + rw * 16 + g * 4 + r) * H + n] = f2bf(acc[nt][r] * QSCALE);
        }
    }
}

// ---------------------------------------------------------------------------
// Kernel 3: causal flash attention + fused merge.
// 1024 blocks x 256 thr (4 waves), 32 q-rows/wave.  bid = qti*32 + sp*4 + b.
// Each split block writes bf16 partials, __threadfence, atomicAdd sem;
// the 8th arriver acquires and writes the normalized f32 output rows.
// ---------------------------------------------------------------------------
__global__ __launch_bounds__(256) void attn(
    const unsigned short* __restrict__ Qg, const unsigned short* __restrict__ Kg,
    const unsigned short* __restrict__ VTg,
    unsigned short* __restrict__ Opb, float* __restrict__ lpart,
    int* __restrict__ sem, float* __restrict__ out) {
    __shared__ __align__(16) unsigned short ks[2][64 * 64];   // 2 x 8 KB
    __shared__ __align__(16) unsigned short vs[2][64 * 64];   // 2 x 8 KB
    __shared__ int lastFlag;

    const int t = threadIdx.x, lane = t & 63, w = t >> 6;
    const int bid = blockIdx.x;
    const int b = bid & 3;
    const int sp = (bid >> 2) & 7;                  // KV split 0..7
    const int qti = bid >> 5;
    const int qt = 31 - qti;                        // heavy-first
    const int q0 = qt * 128;
    const int q0w = q0 + w * 32;                    // wave's first q row
    const int i = lane & 15, g = lane >> 4, g4 = g * 4;
    const int nkv = 2 * qt + 2;

    const unsigned short* Kb = Kg  + (size_t)b * T * H;
    const unsigned short* Vb = VTg + (size_t)b * H * T;

    const int r8 = lane >> 3, sl = lane & 7, sx = sl ^ r8;

    const unsigned short* QrowA = Qg + (size_t)(b * T + q0w + i) * H;
    s16x8 bqa0 = *(const s16x8*)(QrowA + g * 8);
    s16x8 bqa1 = *(const s16x8*)(QrowA + 32 + g * 8);
    const unsigned short* QrowB = QrowA + 16 * H;
    s16x8 bqb0 = *(const s16x8*)(QrowB + g * 8);
    s16x8 bqb1 = *(const s16x8*)(QrowB + 32 + g * 8);

    f32x4 oa[4], ob[4];
#pragma unroll
    for (int nt = 0; nt < 4; ++nt) {
        oa[nt] = (f32x4){0.f, 0.f, 0.f, 0.f};
        ob[nt] = (f32x4){0.f, 0.f, 0.f, 0.f};
    }
    float la = 0.f, lb = 0.f;

    // ---- prologue: stage first tile into buf 0
    if (sp < nkv) {
        const int kv0 = sp * 64;
#pragma unroll
        for (int j = 0; j < 2; ++j) {
            const int row = (w + j * 4) * 8 + r8;
            gl_lds16(Kb + (size_t)(kv0 + row) * H + sx * 8, &ks[0][row * 64 + sl * 8]);
            gl_lds16(Vb + (size_t)row * T + kv0 + sx * 8,   &vs[0][row * 64 + sl * 8]);
        }
    }
    __syncthreads();

    int cur = 0;
    for (int tile = sp; tile < nkv; tile += 8) {
        const int kv = tile * 64;
        if (tile + 8 < nkv) {
            const int kvn = kv + 512;
#pragma unroll
            for (int j = 0; j < 2; ++j) {
                const int row = (w + j * 4) * 8 + r8;
                gl_lds16(Kb + (size_t)(kvn + row) * H + sx * 8, &ks[cur ^ 1][row * 64 + sl * 8]);
                gl_lds16(Vb + (size_t)row * T + kvn + sx * 8,   &vs[cur ^ 1][row * 64 + sl * 8]);
            }
        }

        if (kv <= q0w + 31) {
            s16x8 kb[8];
#pragma unroll
            for (int kst = 0; kst < 2; ++kst)
#pragma unroll
                for (int nt = 0; nt < 4; ++nt)
                    kb[kst * 4 + nt] = *(const s16x8*)
                        &ks[cur][(nt * 16 + i) * 64 + (((kst * 4 + g) ^ (i & 7)) * 8)];

            unsigned pa[8], pb2[8];

            // ===== group a
            {
                f32x4 s[4];
#pragma unroll
                for (int nt = 0; nt < 4; ++nt)
                    s[nt] = (f32x4){-MBASE, -MBASE, -MBASE, -MBASE};
#pragma unroll
                for (int nt = 0; nt < 4; ++nt)
                    s[nt] = __builtin_amdgcn_mfma_f32_16x16x32_bf16(kb[nt], bqa0, s[nt], 0, 0, 0);
#pragma unroll
                for (int nt = 0; nt < 4; ++nt)
                    s[nt] = __builtin_amdgcn_mfma_f32_16x16x32_bf16(kb[4 + nt], bqa1, s[nt], 0, 0, 0);
                if (kv + 63 > q0w) {
                    const int thr = q0w + i - kv;
#pragma unroll
                    for (int nt = 0; nt < 4; ++nt)
#pragma unroll
                        for (int r = 0; r < 4; ++r)
                            if (nt * 16 + g4 + r > thr) s[nt][r] = -INFINITY;
                }
#pragma unroll
                for (int nt = 0; nt < 4; ++nt)
#pragma unroll
                    for (int r = 0; r < 4; ++r)
                        s[nt][r] = exp2f(s[nt][r]);
#pragma unroll
                for (int nt = 0; nt < 4; ++nt) {
                    pa[nt * 2]     = cvt_pk_bf16(s[nt][0], s[nt][1]);
                    pa[nt * 2 + 1] = cvt_pk_bf16(s[nt][2], s[nt][3]);
                }
                la += ((s[0][0] + s[0][1]) + (s[0][2] + s[0][3]))
                    + ((s[1][0] + s[1][1]) + (s[1][2] + s[1][3]))
                    + ((s[2][0] + s[2][1]) + (s[2][2] + s[2][3]))
                    + ((s[3][0] + s[3][1]) + (s[3][2] + s[3][3]));
            }

            // ===== group b (kb still live)
            {
                f32x4 s[4];
#pragma unroll
                for (int nt = 0; nt < 4; ++nt)
                    s[nt] = (f32x4){-MBASE, -MBASE, -MBASE, -MBASE};
#pragma unroll
                for (int nt = 0; nt < 4; ++nt)
                    s[nt] = __builtin_amdgcn_mfma_f32_16x16x32_bf16(kb[nt], bqb0, s[nt], 0, 0, 0);
#pragma unroll
                for (int nt = 0; nt < 4; ++nt)
                    s[nt] = __builtin_amdgcn_mfma_f32_16x16x32_bf16(kb[4 + nt], bqb1, s[nt], 0, 0, 0);
                if (kv + 63 > q0w + 16) {
                    const int thr = q0w + 16 + i - kv;
#pragma unroll
                    for (int nt = 0; nt < 4; ++nt)
#pragma unroll
                        for (int r = 0; r < 4; ++r)
                            if (nt * 16 + g4 + r > thr) s[nt][r] = -INFINITY;
                }
#pragma unroll
                for (int nt = 0; nt < 4; ++nt)
#pragma unroll
                    for (int r = 0; r < 4; ++r)
                        s[nt][r] = exp2f(s[nt][r]);
#pragma unroll
                for (int nt = 0; nt < 4; ++nt) {
                    pb2[nt * 2]     = cvt_pk_bf16(s[nt][0], s[nt][1]);
                    pb2[nt * 2 + 1] = cvt_pk_bf16(s[nt][2], s[nt][3]);
                }
                lb += ((s[0][0] + s[0][1]) + (s[0][2] + s[0][3]))
                    + ((s[1][0] + s[1][1]) + (s[1][2] + s[1][3]))
                    + ((s[2][0] + s[2][1]) + (s[2][2] + s[2][3]))
                    + ((s[3][0] + s[3][1]) + (s[3][2] + s[3][3]));
            }

            // ---- V fragments (kb dead), then PV a & b
            s16x8 vb[8];
#pragma unroll
            for (int kst = 0; kst < 2; ++kst)
#pragma unroll
                for (int nt = 0; nt < 4; ++nt)
                    vb[kst * 4 + nt] = *(const s16x8*)
                        &vs[cur][(nt * 16 + i) * 64 + (((kst * 4 + g) ^ (i & 7)) * 8)];

#pragma unroll
            for (int kst = 0; kst < 2; ++kst) {
                union { unsigned u[4]; s16x8 v; } fa, fb;
                fa.u[0] = pa[4 * kst];      fa.u[1] = pa[4 * kst + 1];
                fa.u[2] = pa[4 * kst + 2];  fa.u[3] = pa[4 * kst + 3];
                fb.u[0] = pb2[4 * kst];     fb.u[1] = pb2[4 * kst + 1];
                fb.u[2] = pb2[4 * kst + 2]; fb.u[3] = pb2[4 * kst + 3];
#pragma unroll
                for (int nt = 0; nt < 4; ++nt) {
                    oa[nt] = __builtin_amdgcn_mfma_f32_16x16x32_bf16(vb[kst * 4 + nt], fa.v, oa[nt], 0, 0, 0);
                    ob[nt] = __builtin_amdgcn_mfma_f32_16x16x32_bf16(vb[kst * 4 + nt], fb.v, ob[nt], 0, 0, 0);
                }
            }
        }

        __syncthreads();
        cur ^= 1;
    }

    // ---- write bf16 partials
    la += __shfl_xor(la, 16);  la += __shfl_xor(la, 32);
    lb += __shfl_xor(lb, 16);  lb += __shfl_xor(lb, 32);
    unsigned short* opA = Opb + ((size_t)bid * 128 + w * 32 + i) * 64;
    unsigned short* opB = opA + 16 * 64;
#pragma unroll
    for (int nt = 0; nt < 4; ++nt) {
        u32x2 pk;
        pk[0] = cvt_pk_bf16(oa[nt][0], oa[nt][1]);
        pk[1] = cvt_pk_bf16(oa[nt][2], oa[nt][3]);
        *(u32x2*)(opA + nt * 16 + g4) = pk;
        pk[0] = cvt_pk_bf16(ob[nt][0], ob[nt][1]);
        pk[1] = cvt_pk_bf16(ob[nt][2], ob[nt][3]);
        *(u32x2*)(opB + nt * 16 + g4) = pk;
    }
    if (g == 0) {
        lpart[(size_t)bid * 128 + w * 32 + i]      = la;
        lpart[(size_t)bid * 128 + w * 32 + 16 + i] = lb;
    }

    // ---- semaphore: last of the 8 split blocks merges and writes out
    __threadfence();                                 // release partials (device scope)
    __syncthreads();                                 // all stores in block done
    if (t == 0) {
        int prev = atomicAdd(&sem[qti * 4 + b], 1);
        lastFlag = (prev == 7) ? 1 : 0;
    }
    __syncthreads();
    if (lastFlag == 0) return;
    __threadfence();                                 // acquire others' partials

    for (int item = t; item < 2048; item += 256) {   // 128 rows x 16 f32x4 chunks
        const int r = item >> 4, c4 = (item & 15) * 4;
        float L = 0.f;
        f32x4 o = (f32x4){0.f, 0.f, 0.f, 0.f};
#pragma unroll
        for (int sp2 = 0; sp2 < 8; ++sp2) {
            const int bidp = qti * 32 + sp2 * 4 + b;
            L += __hip_atomic_load(&lpart[(size_t)bidp * 128 + r],
                                   __ATOMIC_RELAXED, __HIP_MEMORY_SCOPE_AGENT);
            unsigned long long d = __hip_atomic_load(
                (const unsigned long long*)&Opb[((size_t)bidp * 128 + r) * 64 + c4],
                __ATOMIC_RELAXED, __HIP_MEMORY_SCOPE_AGENT);
#pragma unroll
            for (int k = 0; k < 4; ++k) {
                union { unsigned u; float f; } cv;
                cv.u = (unsigned)((d >> (16 * k)) & 0xFFFFu) << 16;
                o[k] += cv.f;
            }
        }
        const float inv = 1.0f / L;
        f32x4 res = (f32x4){o[0] * inv, o[1] * inv, o[2] * inv, o[3] * inv};
        *(f32x4*)&out[((size_t)(b * T + q0 + r)) * 64 + c4] = res;
    }
}

// ---------------------------------------------------------------------------
extern "C" void kernel_launch(void* const* d_in, const int* in_sizes, int n_in,
                              void* d_out, int out_size, void* d_ws, size_t ws_size,
                              hipStream_t stream) {
    (void)in_sizes; (void)n_in; (void)out_size; (void)ws_size;
    const float* x  = (const float*)d_in[0];
    const float* Wq = (const float*)d_in[1];
    const float* Wk = (const float*)d_in[2];
    const float* Wv = (const float*)d_in[3];
    float* out = (float*)d_out;

    char* ws = (char*)d_ws;
    unsigned short* Q  = (unsigned short*)(ws);
    unsigned short* K  = (unsigned short*)(ws + (size_t)1 * M * H * 2);
    unsigned short* VT = (unsigned short*)(ws + (size_t)3 * M * H * 2);
    unsigned short* Wt = (unsigned short*)(ws + (size_t)4 * M * H * 2);     // 384 KB
    unsigned short* Opb = (unsigned short*)(ws + (size_t)4 * M * H * 2 + 512 * 1024);  // 16.8 MB
    float* lpart = (float*)(ws + (size_t)4 * M * H * 2 + 512 * 1024
                            + (size_t)1024 * 128 * 64 * 2);                 // 512 KB
    int* sem = (int*)(ws + (size_t)4 * M * H * 2 + 512 * 1024
                      + (size_t)1024 * 128 * 64 * 2 + 1024 * 1024);         // 512 B
    // total workspace ~27 MB

    hipMemsetAsync(sem, 0, 128 * sizeof(int), stream);
    prep_w<<<192, 256, 0, stream>>>(Wq, Wk, Wv, Wt);
    qkv_proj<<<M / 32, 512, 0, stream>>>(x, Wt, Q, K, VT);
    attn<<<1024, 256, 0, stream>>>(Q, K, VT, Opb, lpart, sem, out);
}

// Round 15
// 53.654 us; speedup vs baseline: 3.9082x; 3.9082x over previous
//
#include <hip/hip_runtime.h>

// SelfAttentionHead: B=4, T=4096, C=1024, H=64, causal, f32 in/out.
// prep_w -> qkv_proj (LDS dbuf MFMA GEMM; Q pre-scaled; V written DIRECTLY
// in key-permuted VT layout) -> attn (triple-buffered LDS K/V staged 2 tiles
// ahead, counted-vmcnt barriers (no drain), swapped QK^T, fixed-base softmax,
// 32 q-rows/wave, 8-way KV split) -> merge8 (linear combine, bf16 partials).

typedef short  s16x8 __attribute__((ext_vector_type(8)));
typedef float  f32x4 __attribute__((ext_vector_type(4)));
typedef unsigned u32x2 __attribute__((ext_vector_type(2)));

constexpr int B = 4, T = 4096, C = 1024, H = 64;
constexpr int M = B * T;                    // 16384 tokens
constexpr float LOG2E = 1.44269504088896340736f;
constexpr float QSCALE = 0.125f * LOG2E;    // H^-0.5 * log2(e): s in log2 domain
constexpr float MBASE  = 4.0f * LOG2E;      // fixed softmax base (nat-log 4)

__device__ __forceinline__ unsigned short f2bf(float f) {
    union { float f; unsigned u; } v; v.f = f;
    unsigned r = v.u + 0x7fffu + ((v.u >> 16) & 1u);   // RNE
    return (unsigned short)(r >> 16);
}

__device__ __forceinline__ unsigned cvt_pk_bf16(float lo, float hi) {
    unsigned r;
    asm("v_cvt_pk_bf16_f32 %0, %1, %2" : "=v"(r) : "v"(lo), "v"(hi));
    return r;   // [15:0]=bf16(lo), [31:16]=bf16(hi)
}

__device__ __forceinline__ void gl_lds16(const void* g, void* l) {
    __builtin_amdgcn_global_load_lds(
        (const __attribute__((address_space(1))) unsigned*)g,
        (__attribute__((address_space(3))) unsigned*)l, 16, 0, 0);
}

// ---------------------------------------------------------------------------
// Kernel 1: Wt[n][k] = W_{n/64}[k][n%64] as bf16.
// ---------------------------------------------------------------------------
__global__ void prep_w(const float* __restrict__ Wq, const float* __restrict__ Wk,
                       const float* __restrict__ Wv, unsigned short* __restrict__ Wt) {
    const int n = blockIdx.x;                       // 0..191
    const float* W = (n < 64) ? Wq : (n < 128 ? Wk : Wv);
    const int col = n & 63;
    for (int k = threadIdx.x; k < C; k += blockDim.x)
        Wt[(size_t)n * C + k] = f2bf(W[(size_t)k * H + col]);
}

// ---------------------------------------------------------------------------
// Kernel 2: fused QKV projection.  M=16384,K=1024,N=192 bf16 MFMA.
// 512 blocks x 512 thr (8 waves) share one BM=32 x BN=192 x BK=64
// double-buffered LDS tile.  B staged with global_load_lds (linear dest,
// pre-swizzled source); A reg-staged f32->bf16.  Q pre-scaled by QSCALE.
// V written directly into key-permuted transposed layout VT[b][h][pos].
// ---------------------------------------------------------------------------
__global__ __launch_bounds__(512) void qkv_proj(
    const float* __restrict__ x, const unsigned short* __restrict__ Wt,
    unsigned short* __restrict__ Q, unsigned short* __restrict__ K,
    unsigned short* __restrict__ VT) {
    __shared__ __align__(16) unsigned short ldsA[2][32 * 64];    //  8 KB
    __shared__ __align__(16) unsigned short ldsB[2][192 * 64];   // 48 KB

    const int t = threadIdx.x, lane = t & 63, w = t >> 6;
    const int i = lane & 15, g = lane >> 4;
    const int rowbase = blockIdx.x * 32;
    const int rw = w & 1, nw = w >> 1;              // row-group, N-quarter

    const int arow = t >> 3, aslot = t & 7;
    const float* aga = x + (size_t)(rowbase + arow) * C + ((aslot ^ (arow & 7)) * 8);
    const int awoff = arow * 64 + aslot * 8;
    const bool astage = (t < 256);

    const int brow8 = lane >> 3, bslot = lane & 7;
    const unsigned short* bga[3];
    int bn0[3];
#pragma unroll
    for (int j = 0; j < 3; ++j) {
        bn0[j] = w * 24 + j * 8;
        bga[j] = Wt + (size_t)(bn0[j] + brow8) * C + ((bslot ^ brow8) * 8);
    }

    f32x4 acc[3];
#pragma unroll
    for (int n = 0; n < 3; ++n) acc[n] = (f32x4){0.f, 0.f, 0.f, 0.f};

    {
#pragma unroll
        for (int j = 0; j < 3; ++j)
            gl_lds16(bga[j], &ldsB[0][bn0[j] * 64]);
        if (astage) {
            f32x4 a0 = *(const f32x4*)(aga);
            f32x4 a1 = *(const f32x4*)(aga + 4);
            union { unsigned u[4]; s16x8 v; } av;
            av.u[0] = cvt_pk_bf16(a0[0], a0[1]);
            av.u[1] = cvt_pk_bf16(a0[2], a0[3]);
            av.u[2] = cvt_pk_bf16(a1[0], a1[1]);
            av.u[3] = cvt_pk_bf16(a1[2], a1[3]);
            *(s16x8*)&ldsA[0][awoff] = av.v;
        }
    }
    __syncthreads();

    for (int it = 0; it < 16; ++it) {
        const int cur = it & 1, nxt = cur ^ 1;
        const int kc = (it + 1) * 64;
        f32x4 a0, a1;
        const bool more = (it < 15);
        if (more) {
            if (astage) {
                a0 = *(const f32x4*)(aga + kc);
                a1 = *(const f32x4*)(aga + kc + 4);
            }
#pragma unroll
            for (int j = 0; j < 3; ++j)
                gl_lds16(bga[j] + kc, &ldsB[nxt][bn0[j] * 64]);
        }
#pragma unroll
        for (int kst = 0; kst < 2; ++kst) {
            const int c = kst * 4 + g;
            s16x8 a = *(const s16x8*)&ldsA[cur][(rw * 16 + i) * 64 + ((c ^ (i & 7)) * 8)];
#pragma unroll
            for (int nt = 0; nt < 3; ++nt) {
                int n = nw * 48 + nt * 16 + i;        // n&7 == i&7
                s16x8 b = *(const s16x8*)&ldsB[cur][n * 64 + ((c ^ (i & 7)) * 8)];
                acc[nt] = __builtin_amdgcn_mfma_f32_16x16x32_bf16(a, b, acc[nt], 0, 0, 0);
            }
        }
        if (more && astage) {
            union { unsigned u[4]; s16x8 v; } av;
            av.u[0] = cvt_pk_bf16(a0[0], a0[1]);
            av.u[1] = cvt_pk_bf16(a0[2], a0[3]);
            av.u[2] = cvt_pk_bf16(a1[0], a1[1]);
            av.u[3] = cvt_pk_bf16(a1[2], a1[3]);
            *(s16x8*)&ldsA[nxt][awoff] = av.v;
        }
        __syncthreads();
    }

    // epilogue: D layout col=lane&15, row=4*(lane>>4)+r; per-nt region uniform
#pragma unroll
    for (int nt = 0; nt < 3; ++nt) {
        const int base = nw * 48 + nt * 16;
        const int n = base + i;
        if (base >= 128) {          // V -> direct key-permuted VT store
            const int h = n - 128;
            const int bb = rowbase >> 12, tb = rowbase & 4095;
            u32x2 pk;
            pk[0] = cvt_pk_bf16(acc[nt][0], acc[nt][1]);
            pk[1] = cvt_pk_bf16(acc[nt][2], acc[nt][3]);
            *(u32x2*)(VT + (size_t)(bb * H + h) * T + tb + g * 8 + rw * 4) = pk;
        } else if (base >= 64) {    // K
#pragma unroll
            for (int r = 0; r < 4; ++r)
                K[(size_t)(rowbase + rw * 16 + g * 4 + r) * H + (n - 64)] = f2bf(acc[nt][r]);
        } else {                    // Q (pre-scaled)
#pragma unroll
            for (int r = 0; r < 4; ++r)
                Q[(size_t)(rowbase + rw * 16 + g * 4 + r) * H + n] = f2bf(acc[nt][r] * QSCALE);
        }
    }
}

// ---------------------------------------------------------------------------
// Kernel 3: causal flash attention.  Triple-buffered LDS K/V, staged 2 tiles
// ahead; barriers use counted s_waitcnt vmcnt(4) (this iteration's 4 gl_lds
// stay in flight) instead of __syncthreads' vmcnt(0) drain.
// 1024 blocks x 256 thr (4 waves), 32 q-rows/wave.  bid = qti*32 + sp*4 + b:
// qt = 31-qti (heavy-first, 128 q-rows/block), sp = KV split 0..7, b = batch
// (bid%8 -> XCDs {b, b+4} serve only batch b).  Fixed-base softmax: no max
// tracking, no cross-lane ops in the loop.  bf16 un-normalized O partials.
// ---------------------------------------------------------------------------
__global__ __launch_bounds__(256) void attn(
    const unsigned short* __restrict__ Qg, const unsigned short* __restrict__ Kg,
    const unsigned short* __restrict__ VTg,
    unsigned short* __restrict__ Opb, float* __restrict__ lpart) {
    __shared__ __align__(16) unsigned short ks[3][64 * 64];   // 3 x 8 KB
    __shared__ __align__(16) unsigned short vs[3][64 * 64];   // 3 x 8 KB

    const int t = threadIdx.x, lane = t & 63, w = t >> 6;
    const int bid = blockIdx.x;
    const int b = bid & 3;
    const int sp = (bid >> 2) & 7;                  // KV split 0..7
    const int qt = 31 - (bid >> 5);                 // heavy-first
    const int q0 = qt * 128;
    const int q0w = q0 + w * 32;                    // wave's first q row
    const int i = lane & 15, g = lane >> 4, g4 = g * 4;
    const int nkv = 2 * qt + 2;
    const int nTiles = (sp < nkv) ? ((nkv - sp + 7) >> 3) : 0;

    const unsigned short* Kb = Kg  + (size_t)b * T * H;
    const unsigned short* Vb = VTg + (size_t)b * H * T;

    // staging map: lane -> rows (w+j*4)*8 + (lane>>3), slot lane&7
    const int r8 = lane >> 3, sl = lane & 7, sx = sl ^ r8;

    // Q fragments for both 16-row groups (col=i=q, k=h)
    const unsigned short* QrowA = Qg + (size_t)(b * T + q0w + i) * H;
    s16x8 bqa0 = *(const s16x8*)(QrowA + g * 8);
    s16x8 bqa1 = *(const s16x8*)(QrowA + 32 + g * 8);
    const unsigned short* QrowB = QrowA + 16 * H;
    s16x8 bqb0 = *(const s16x8*)(QrowB + g * 8);
    s16x8 bqb1 = *(const s16x8*)(QrowB + 32 + g * 8);

    f32x4 oa[4], ob[4];
#pragma unroll
    for (int nt = 0; nt < 4; ++nt) {
        oa[nt] = (f32x4){0.f, 0.f, 0.f, 0.f};
        ob[nt] = (f32x4){0.f, 0.f, 0.f, 0.f};
    }
    float la = 0.f, lb = 0.f;

    // ---- prologue: stage tiles sp, sp+8 into buffers 0, 1 (4 gl_lds each)
    if (nTiles > 0) {
        const int kv0 = sp * 64;
#pragma unroll
        for (int j = 0; j < 2; ++j) {
            const int row = (w + j * 4) * 8 + r8;
            gl_lds16(Kb + (size_t)(kv0 + row) * H + sx * 8, &ks[0][row * 64 + sl * 8]);
            gl_lds16(Vb + (size_t)row * T + kv0 + sx * 8,   &vs[0][row * 64 + sl * 8]);
        }
    }
    if (nTiles > 1) {
        const int kv1 = (sp + 8) * 64;
#pragma unroll
        for (int j = 0; j < 2; ++j) {
            const int row = (w + j * 4) * 8 + r8;
            gl_lds16(Kb + (size_t)(kv1 + row) * H + sx * 8, &ks[1][row * 64 + sl * 8]);
            gl_lds16(Vb + (size_t)row * T + kv1 + sx * 8,   &vs[1][row * 64 + sl * 8]);
        }
        asm volatile("s_waitcnt vmcnt(4)\n\ts_barrier" ::: "memory");
    } else {
        asm volatile("s_waitcnt vmcnt(0)\n\ts_barrier" ::: "memory");
    }

    for (int n = 0; n < nTiles; ++n) {
        const int tile = sp + n * 8;
        const int kv = tile * 64;
        const int cur = n % 3;
        const bool issue = (n + 2 < nTiles);

        // ---- stage tile+16 into buffer (n+2)%3 (async; 2 tiles of cover)
        if (issue) {
            const int nxt = (n + 2) % 3;
            const int kvn = kv + 1024;
#pragma unroll
            for (int j = 0; j < 2; ++j) {
                const int row = (w + j * 4) * 8 + r8;
                gl_lds16(Kb + (size_t)(kvn + row) * H + sx * 8, &ks[nxt][row * 64 + sl * 8]);
                gl_lds16(Vb + (size_t)row * T + kvn + sx * 8,   &vs[nxt][row * 64 + sl * 8]);
            }
        }

        // ---- skip if both q-groups entirely below the tile
        if (kv <= q0w + 31) {
            // ---- K fragments (shared by both q-groups)
            s16x8 kb[8];
#pragma unroll
            for (int kst = 0; kst < 2; ++kst)
#pragma unroll
                for (int nt = 0; nt < 4; ++nt)
                    kb[kst * 4 + nt] = *(const s16x8*)
                        &ks[cur][(nt * 16 + i) * 64 + (((kst * 4 + g) ^ (i & 7)) * 8)];

            unsigned pa[8], pb2[8];

            // ===== group a: QK^T -> mask -> exp -> pack
            {
                f32x4 s[4];
#pragma unroll
                for (int nt = 0; nt < 4; ++nt)
                    s[nt] = (f32x4){-MBASE, -MBASE, -MBASE, -MBASE};
#pragma unroll
                for (int nt = 0; nt < 4; ++nt)
                    s[nt] = __builtin_amdgcn_mfma_f32_16x16x32_bf16(kb[nt], bqa0, s[nt], 0, 0, 0);
#pragma unroll
                for (int nt = 0; nt < 4; ++nt)
                    s[nt] = __builtin_amdgcn_mfma_f32_16x16x32_bf16(kb[4 + nt], bqa1, s[nt], 0, 0, 0);
                if (kv + 63 > q0w) {
                    const int thr = q0w + i - kv;
#pragma unroll
                    for (int nt = 0; nt < 4; ++nt)
#pragma unroll
                        for (int r = 0; r < 4; ++r)
                            if (nt * 16 + g4 + r > thr) s[nt][r] = -INFINITY;
                }
#pragma unroll
                for (int nt = 0; nt < 4; ++nt)
#pragma unroll
                    for (int r = 0; r < 4; ++r)
                        s[nt][r] = exp2f(s[nt][r]);
#pragma unroll
                for (int nt = 0; nt < 4; ++nt) {
                    pa[nt * 2]     = cvt_pk_bf16(s[nt][0], s[nt][1]);
                    pa[nt * 2 + 1] = cvt_pk_bf16(s[nt][2], s[nt][3]);
                }
                la += ((s[0][0] + s[0][1]) + (s[0][2] + s[0][3]))
                    + ((s[1][0] + s[1][1]) + (s[1][2] + s[1][3]))
                    + ((s[2][0] + s[2][1]) + (s[2][2] + s[2][3]))
                    + ((s[3][0] + s[3][1]) + (s[3][2] + s[3][3]));
            }

            // ===== group b: QK^T -> mask -> exp -> pack (kb still live)
            {
                f32x4 s[4];
#pragma unroll
                for (int nt = 0; nt < 4; ++nt)
                    s[nt] = (f32x4){-MBASE, -MBASE, -MBASE, -MBASE};
#pragma unroll
                for (int nt = 0; nt < 4; ++nt)
                    s[nt] = __builtin_amdgcn_mfma_f32_16x16x32_bf16(kb[nt], bqb0, s[nt], 0, 0, 0);
#pragma unroll
                for (int nt = 0; nt < 4; ++nt)
                    s[nt] = __builtin_amdgcn_mfma_f32_16x16x32_bf16(kb[4 + nt], bqb1, s[nt], 0, 0, 0);
                if (kv + 63 > q0w + 16) {
                    const int thr = q0w + 16 + i - kv;
#pragma unroll
                    for (int nt = 0; nt < 4; ++nt)
#pragma unroll
                        for (int r = 0; r < 4; ++r)
                            if (nt * 16 + g4 + r > thr) s[nt][r] = -INFINITY;
                }
#pragma unroll
                for (int nt = 0; nt < 4; ++nt)
#pragma unroll
                    for (int r = 0; r < 4; ++r)
                        s[nt][r] = exp2f(s[nt][r]);
#pragma unroll
                for (int nt = 0; nt < 4; ++nt) {
                    pb2[nt * 2]     = cvt_pk_bf16(s[nt][0], s[nt][1]);
                    pb2[nt * 2 + 1] = cvt_pk_bf16(s[nt][2], s[nt][3]);
                }
                lb += ((s[0][0] + s[0][1]) + (s[0][2] + s[0][3]))
                    + ((s[1][0] + s[1][1]) + (s[1][2] + s[1][3]))
                    + ((s[2][0] + s[2][1]) + (s[2][2] + s[2][3]))
                    + ((s[3][0] + s[3][1]) + (s[3][2] + s[3][3]));
            }

            // ---- V fragments (kb dead -> registers reused), then PV a & b
            s16x8 vb[8];
#pragma unroll
            for (int kst = 0; kst < 2; ++kst)
#pragma unroll
                for (int nt = 0; nt < 4; ++nt)
                    vb[kst * 4 + nt] = *(const s16x8*)
                        &vs[cur][(nt * 16 + i) * 64 + (((kst * 4 + g) ^ (i & 7)) * 8)];

#pragma unroll
            for (int kst = 0; kst < 2; ++kst) {
                union { unsigned u[4]; s16x8 v; } fa, fb;
                fa.u[0] = pa[4 * kst];      fa.u[1] = pa[4 * kst + 1];
                fa.u[2] = pa[4 * kst + 2];  fa.u[3] = pa[4 * kst + 3];
                fb.u[0] = pb2[4 * kst];     fb.u[1] = pb2[4 * kst + 1];
                fb.u[2] = pb2[4 * kst + 2]; fb.u[3] = pb2[4 * kst + 3];
#pragma unroll
                for (int nt = 0; nt < 4; ++nt) {
                    oa[nt] = __builtin_amdgcn_mfma_f32_16x16x32_bf16(vb[kst * 4 + nt], fa.v, oa[nt], 0, 0, 0);
                    ob[nt] = __builtin_amdgcn_mfma_f32_16x16x32_bf16(vb[kst * 4 + nt], fb.v, ob[nt], 0, 0, 0);
                }
            }
        }

        // ---- counted-vmcnt barrier: this iteration's 4 loads stay in flight
        if (issue) asm volatile("s_waitcnt vmcnt(4)\n\ts_barrier" ::: "memory");
        else       asm volatile("s_waitcnt vmcnt(0)\n\ts_barrier" ::: "memory");
    }

    // ---- reduce l across the 4 lane-groups (once), write bf16 partials
    la += __shfl_xor(la, 16);  la += __shfl_xor(la, 32);
    lb += __shfl_xor(lb, 16);  lb += __shfl_xor(lb, 32);
    unsigned short* opA = Opb + ((size_t)bid * 128 + w * 32 + i) * 64;
    unsigned short* opB = opA + 16 * 64;
#pragma unroll
    for (int nt = 0; nt < 4; ++nt) {
        u32x2 pk;
        pk[0] = cvt_pk_bf16(oa[nt][0], oa[nt][1]);
        pk[1] = cvt_pk_bf16(oa[nt][2], oa[nt][3]);
        *(u32x2*)(opA + nt * 16 + g4) = pk;
        pk[0] = cvt_pk_bf16(ob[nt][0], ob[nt][1]);
        pk[1] = cvt_pk_bf16(ob[nt][2], ob[nt][3]);
        *(u32x2*)(opB + nt * 16 + g4) = pk;
    }
    if (g == 0) {
        lpart[(size_t)bid * 128 + w * 32 + i]      = la;
        lpart[(size_t)bid * 128 + w * 32 + 16 + i] = lb;
    }
}

// ---------------------------------------------------------------------------
// Kernel 4: linear merge of the 8 KV splits (fixed base -> no max logic).
// 1024 blocks x 256 thr; thread -> one f32x4 of one output row.
// ---------------------------------------------------------------------------
__global__ __launch_bounds__(256) void merge8(
    const unsigned short* __restrict__ Opb, const float* __restrict__ lpart,
    float* __restrict__ out) {
    const int idx = blockIdx.x * 256 + threadIdx.x;     // 262144 = 16384 x 16
    const int row = idx >> 4, c4 = (idx & 15) * 4;
    const int b = row >> 12, q = row & 4095;
    const int qt = q >> 7, r = q & 127;
    const int qti = 31 - qt;

    float L = 0.f;
    f32x4 o = (f32x4){0.f, 0.f, 0.f, 0.f};
#pragma unroll
    for (int sp = 0; sp < 8; ++sp) {
        const int bidp = qti * 32 + sp * 4 + b;
        L += lpart[(size_t)bidp * 128 + r];
        union { unsigned long long d; unsigned short s[4]; } v;
        v.d = *(const unsigned long long*)&Opb[((size_t)bidp * 128 + r) * 64 + c4];
#pragma unroll
        for (int k = 0; k < 4; ++k) {
            union { unsigned u; float f; } cv;
            cv.u = (unsigned)v.s[k] << 16;
            o[k] += cv.f;
        }
    }
    const float inv = 1.0f / L;
    f32x4 res = (f32x4){o[0] * inv, o[1] * inv, o[2] * inv, o[3] * inv};
    *(f32x4*)&out[(size_t)row * 64 + c4] = res;
}

// ---------------------------------------------------------------------------
extern "C" void kernel_launch(void* const* d_in, const int* in_sizes, int n_in,
                              void* d_out, int out_size, void* d_ws, size_t ws_size,
                              hipStream_t stream) {
    (void)in_sizes; (void)n_in; (void)out_size; (void)ws_size;
    const float* x  = (const float*)d_in[0];
    const float* Wq = (const float*)d_in[1];
    const float* Wk = (const float*)d_in[2];
    const float* Wv = (const float*)d_in[3];
    float* out = (float*)d_out;

    char* ws = (char*)d_ws;
    unsigned short* Q  = (unsigned short*)(ws);
    unsigned short* K  = (unsigned short*)(ws + (size_t)1 * M * H * 2);
    unsigned short* VT = (unsigned short*)(ws + (size_t)3 * M * H * 2);
    unsigned short* Wt = (unsigned short*)(ws + (size_t)4 * M * H * 2);     // 384 KB
    unsigned short* Opb = (unsigned short*)(ws + (size_t)4 * M * H * 2 + 512 * 1024);  // 16.8 MB
    float* lpart = (float*)(ws + (size_t)4 * M * H * 2 + 512 * 1024
                            + (size_t)1024 * 128 * 64 * 2);                 // 512 KB
    // total workspace ~26 MB

    prep_w<<<192, 256, 0, stream>>>(Wq, Wk, Wv, Wt);
    qkv_proj<<<M / 32, 512, 0, stream>>>(x, Wt, Q, K, VT);
    attn<<<1024, 256, 0, stream>>>(Q, K, VT, Opb, lpart);
    merge8<<<1024, 256, 0, stream>>>(Opb, lpart, out);
}

// Round 16
// 50.767 us; speedup vs baseline: 4.1305x; 1.0569x over previous
//
#include <hip/hip_runtime.h>

// SelfAttentionHead: B=4, T=4096, C=1024, H=64, causal, f32 in/out.
// prep_w -> qkv_proj (LDS dbuf MFMA GEMM; Q pre-scaled; V written DIRECTLY
// in key-permuted VT layout) -> attn (triple-buffered LDS K/V staged 2 tiles
// ahead, counted-vmcnt barriers, swapped QK^T, fixed-base softmax with raw
// v_exp_f32 + MFMA-C-operand init, 32 q-rows/wave, 8-way KV split) ->
// merge8 (linear combine, bf16 partials).

typedef short  s16x8 __attribute__((ext_vector_type(8)));
typedef float  f32x4 __attribute__((ext_vector_type(4)));
typedef unsigned u32x2 __attribute__((ext_vector_type(2)));

constexpr int B = 4, T = 4096, C = 1024, H = 64;
constexpr int M = B * T;                    // 16384 tokens
constexpr float LOG2E = 1.44269504088896340736f;
constexpr float QSCALE = 0.125f * LOG2E;    // H^-0.5 * log2(e): s in log2 domain
constexpr float MBASE  = 4.0f * LOG2E;      // fixed softmax base (nat-log 4)

__device__ __forceinline__ unsigned short f2bf(float f) {
    union { float f; unsigned u; } v; v.f = f;
    unsigned r = v.u + 0x7fffu + ((v.u >> 16) & 1u);   // RNE
    return (unsigned short)(r >> 16);
}

__device__ __forceinline__ unsigned cvt_pk_bf16(float lo, float hi) {
    unsigned r;
    asm("v_cvt_pk_bf16_f32 %0, %1, %2" : "=v"(r) : "v"(lo), "v"(hi));
    return r;   // [15:0]=bf16(lo), [31:16]=bf16(hi)
}

__device__ __forceinline__ float vexp2(float x) {    // raw v_exp_f32: 2^x
    float r;
    asm("v_exp_f32 %0, %1" : "=v"(r) : "v"(x));
    return r;
}

__device__ __forceinline__ void gl_lds16(const void* g, void* l) {
    __builtin_amdgcn_global_load_lds(
        (const __attribute__((address_space(1))) unsigned*)g,
        (__attribute__((address_space(3))) unsigned*)l, 16, 0, 0);
}

// ---------------------------------------------------------------------------
// Kernel 1: Wt[n][k] = W_{n/64}[k][n%64] as bf16.
// ---------------------------------------------------------------------------
__global__ void prep_w(const float* __restrict__ Wq, const float* __restrict__ Wk,
                       const float* __restrict__ Wv, unsigned short* __restrict__ Wt) {
    const int n = blockIdx.x;                       // 0..191
    const float* W = (n < 64) ? Wq : (n < 128 ? Wk : Wv);
    const int col = n & 63;
    for (int k = threadIdx.x; k < C; k += blockDim.x)
        Wt[(size_t)n * C + k] = f2bf(W[(size_t)k * H + col]);
}

// ---------------------------------------------------------------------------
// Kernel 2: fused QKV projection.  M=16384,K=1024,N=192 bf16 MFMA.
// 512 blocks x 512 thr (8 waves) share one BM=32 x BN=192 x BK=64
// double-buffered LDS tile.  B staged with global_load_lds (linear dest,
// pre-swizzled source); A reg-staged f32->bf16.  Q pre-scaled by QSCALE.
// V written directly into key-permuted transposed layout VT[b][h][pos].
// ---------------------------------------------------------------------------
__global__ __launch_bounds__(512) void qkv_proj(
    const float* __restrict__ x, const unsigned short* __restrict__ Wt,
    unsigned short* __restrict__ Q, unsigned short* __restrict__ K,
    unsigned short* __restrict__ VT) {
    __shared__ __align__(16) unsigned short ldsA[2][32 * 64];    //  8 KB
    __shared__ __align__(16) unsigned short ldsB[2][192 * 64];   // 48 KB

    const int t = threadIdx.x, lane = t & 63, w = t >> 6;
    const int i = lane & 15, g = lane >> 4;
    const int rowbase = blockIdx.x * 32;
    const int rw = w & 1, nw = w >> 1;              // row-group, N-quarter

    const int arow = t >> 3, aslot = t & 7;
    const float* aga = x + (size_t)(rowbase + arow) * C + ((aslot ^ (arow & 7)) * 8);
    const int awoff = arow * 64 + aslot * 8;
    const bool astage = (t < 256);

    const int brow8 = lane >> 3, bslot = lane & 7;
    const unsigned short* bga[3];
    int bn0[3];
#pragma unroll
    for (int j = 0; j < 3; ++j) {
        bn0[j] = w * 24 + j * 8;
        bga[j] = Wt + (size_t)(bn0[j] + brow8) * C + ((bslot ^ brow8) * 8);
    }

    f32x4 acc[3];
#pragma unroll
    for (int n = 0; n < 3; ++n) acc[n] = (f32x4){0.f, 0.f, 0.f, 0.f};

    {
#pragma unroll
        for (int j = 0; j < 3; ++j)
            gl_lds16(bga[j], &ldsB[0][bn0[j] * 64]);
        if (astage) {
            f32x4 a0 = *(const f32x4*)(aga);
            f32x4 a1 = *(const f32x4*)(aga + 4);
            union { unsigned u[4]; s16x8 v; } av;
            av.u[0] = cvt_pk_bf16(a0[0], a0[1]);
            av.u[1] = cvt_pk_bf16(a0[2], a0[3]);
            av.u[2] = cvt_pk_bf16(a1[0], a1[1]);
            av.u[3] = cvt_pk_bf16(a1[2], a1[3]);
            *(s16x8*)&ldsA[0][awoff] = av.v;
        }
    }
    __syncthreads();

    for (int it = 0; it < 16; ++it) {
        const int cur = it & 1, nxt = cur ^ 1;
        const int kc = (it + 1) * 64;
        f32x4 a0, a1;
        const bool more = (it < 15);
        if (more) {
            if (astage) {
                a0 = *(const f32x4*)(aga + kc);
                a1 = *(const f32x4*)(aga + kc + 4);
            }
#pragma unroll
            for (int j = 0; j < 3; ++j)
                gl_lds16(bga[j] + kc, &ldsB[nxt][bn0[j] * 64]);
        }
#pragma unroll
        for (int kst = 0; kst < 2; ++kst) {
            const int c = kst * 4 + g;
            s16x8 a = *(const s16x8*)&ldsA[cur][(rw * 16 + i) * 64 + ((c ^ (i & 7)) * 8)];
#pragma unroll
            for (int nt = 0; nt < 3; ++nt) {
                int n = nw * 48 + nt * 16 + i;        // n&7 == i&7
                s16x8 b = *(const s16x8*)&ldsB[cur][n * 64 + ((c ^ (i & 7)) * 8)];
                acc[nt] = __builtin_amdgcn_mfma_f32_16x16x32_bf16(a, b, acc[nt], 0, 0, 0);
            }
        }
        if (more && astage) {
            union { unsigned u[4]; s16x8 v; } av;
            av.u[0] = cvt_pk_bf16(a0[0], a0[1]);
            av.u[1] = cvt_pk_bf16(a0[2], a0[3]);
            av.u[2] = cvt_pk_bf16(a1[0], a1[1]);
            av.u[3] = cvt_pk_bf16(a1[2], a1[3]);
            *(s16x8*)&ldsA[nxt][awoff] = av.v;
        }
        __syncthreads();
    }

    // epilogue: D layout col=lane&15, row=4*(lane>>4)+r; per-nt region uniform
#pragma unroll
    for (int nt = 0; nt < 3; ++nt) {
        const int base = nw * 48 + nt * 16;
        const int n = base + i;
        if (base >= 128) {          // V -> direct key-permuted VT store
            const int h = n - 128;
            const int bb = rowbase >> 12, tb = rowbase & 4095;
            u32x2 pk;
            pk[0] = cvt_pk_bf16(acc[nt][0], acc[nt][1]);
            pk[1] = cvt_pk_bf16(acc[nt][2], acc[nt][3]);
            *(u32x2*)(VT + (size_t)(bb * H + h) * T + tb + g * 8 + rw * 4) = pk;
        } else if (base >= 64) {    // K
#pragma unroll
            for (int r = 0; r < 4; ++r)
                K[(size_t)(rowbase + rw * 16 + g * 4 + r) * H + (n - 64)] = f2bf(acc[nt][r]);
        } else {                    // Q (pre-scaled)
#pragma unroll
            for (int r = 0; r < 4; ++r)
                Q[(size_t)(rowbase + rw * 16 + g * 4 + r) * H + n] = f2bf(acc[nt][r] * QSCALE);
        }
    }
}

// ---------------------------------------------------------------------------
// Kernel 3: causal flash attention.  Triple-buffered LDS K/V, staged 2 tiles
// ahead; counted s_waitcnt vmcnt(4) barriers.  1024 blocks x 256 thr
// (4 waves), 32 q-rows/wave.  bid = qti*32 + sp*4 + b.  Fixed-base softmax:
// raw v_exp_f32 (no libm guards), QK accumulator init via MFMA C-operand
// (no v_movs).  bf16 un-normalized O partials.
// ---------------------------------------------------------------------------
__global__ __launch_bounds__(256) void attn(
    const unsigned short* __restrict__ Qg, const unsigned short* __restrict__ Kg,
    const unsigned short* __restrict__ VTg,
    unsigned short* __restrict__ Opb, float* __restrict__ lpart) {
    __shared__ __align__(16) unsigned short ks[3][64 * 64];   // 3 x 8 KB
    __shared__ __align__(16) unsigned short vs[3][64 * 64];   // 3 x 8 KB

    const int t = threadIdx.x, lane = t & 63, w = t >> 6;
    const int bid = blockIdx.x;
    const int b = bid & 3;
    const int sp = (bid >> 2) & 7;                  // KV split 0..7
    const int qt = 31 - (bid >> 5);                 // heavy-first
    const int q0 = qt * 128;
    const int q0w = q0 + w * 32;                    // wave's first q row
    const int i = lane & 15, g = lane >> 4, g4 = g * 4;
    const int nkv = 2 * qt + 2;
    const int nTiles = (sp < nkv) ? ((nkv - sp + 7) >> 3) : 0;

    const unsigned short* Kb = Kg  + (size_t)b * T * H;
    const unsigned short* Vb = VTg + (size_t)b * H * T;

    // staging map: lane -> rows (w+j*4)*8 + (lane>>3), slot lane&7
    const int r8 = lane >> 3, sl = lane & 7, sx = sl ^ r8;

    // Q fragments for both 16-row groups (col=i=q, k=h)
    const unsigned short* QrowA = Qg + (size_t)(b * T + q0w + i) * H;
    s16x8 bqa0 = *(const s16x8*)(QrowA + g * 8);
    s16x8 bqa1 = *(const s16x8*)(QrowA + 32 + g * 8);
    const unsigned short* QrowB = QrowA + 16 * H;
    s16x8 bqb0 = *(const s16x8*)(QrowB + g * 8);
    s16x8 bqb1 = *(const s16x8*)(QrowB + 32 + g * 8);

    const f32x4 minit = (f32x4){-MBASE, -MBASE, -MBASE, -MBASE};

    f32x4 oa[4], ob[4];
#pragma unroll
    for (int nt = 0; nt < 4; ++nt) {
        oa[nt] = (f32x4){0.f, 0.f, 0.f, 0.f};
        ob[nt] = (f32x4){0.f, 0.f, 0.f, 0.f};
    }
    float la = 0.f, lb = 0.f;

    // ---- prologue: stage tiles sp, sp+8 into buffers 0, 1 (4 gl_lds each)
    if (nTiles > 0) {
        const int kv0 = sp * 64;
#pragma unroll
        for (int j = 0; j < 2; ++j) {
            const int row = (w + j * 4) * 8 + r8;
            gl_lds16(Kb + (size_t)(kv0 + row) * H + sx * 8, &ks[0][row * 64 + sl * 8]);
            gl_lds16(Vb + (size_t)row * T + kv0 + sx * 8,   &vs[0][row * 64 + sl * 8]);
        }
    }
    if (nTiles > 1) {
        const int kv1 = (sp + 8) * 64;
#pragma unroll
        for (int j = 0; j < 2; ++j) {
            const int row = (w + j * 4) * 8 + r8;
            gl_lds16(Kb + (size_t)(kv1 + row) * H + sx * 8, &ks[1][row * 64 + sl * 8]);
            gl_lds16(Vb + (size_t)row * T + kv1 + sx * 8,   &vs[1][row * 64 + sl * 8]);
        }
        asm volatile("s_waitcnt vmcnt(4)\n\ts_barrier" ::: "memory");
    } else {
        asm volatile("s_waitcnt vmcnt(0)\n\ts_barrier" ::: "memory");
    }

    for (int n = 0; n < nTiles; ++n) {
        const int tile = sp + n * 8;
        const int kv = tile * 64;
        const int cur = n % 3;
        const bool issue = (n + 2 < nTiles);

        // ---- stage tile+16 into buffer (n+2)%3 (async; 2 tiles of cover)
        if (issue) {
            const int nxt = (n + 2) % 3;
            const int kvn = kv + 1024;
#pragma unroll
            for (int j = 0; j < 2; ++j) {
                const int row = (w + j * 4) * 8 + r8;
                gl_lds16(Kb + (size_t)(kvn + row) * H + sx * 8, &ks[nxt][row * 64 + sl * 8]);
                gl_lds16(Vb + (size_t)row * T + kvn + sx * 8,   &vs[nxt][row * 64 + sl * 8]);
            }
        }

        // ---- skip if both q-groups entirely below the tile
        if (kv <= q0w + 31) {
            // ---- K fragments (shared by both q-groups)
            s16x8 kb[8];
#pragma unroll
            for (int kst = 0; kst < 2; ++kst)
#pragma unroll
                for (int nt = 0; nt < 4; ++nt)
                    kb[kst * 4 + nt] = *(const s16x8*)
                        &ks[cur][(nt * 16 + i) * 64 + (((kst * 4 + g) ^ (i & 7)) * 8)];

            unsigned pa[8], pb2[8];

            // ===== group a: QK^T (C-operand init) -> mask -> exp -> pack
            {
                f32x4 s[4];
#pragma unroll
                for (int nt = 0; nt < 4; ++nt) {
                    s[nt] = __builtin_amdgcn_mfma_f32_16x16x32_bf16(kb[nt], bqa0, minit, 0, 0, 0);
                    s[nt] = __builtin_amdgcn_mfma_f32_16x16x32_bf16(kb[4 + nt], bqa1, s[nt], 0, 0, 0);
                }
                if (kv + 63 > q0w) {
                    const int thr = q0w + i - kv;
#pragma unroll
                    for (int nt = 0; nt < 4; ++nt)
#pragma unroll
                        for (int r = 0; r < 4; ++r)
                            if (nt * 16 + g4 + r > thr) s[nt][r] = -INFINITY;
                }
#pragma unroll
                for (int nt = 0; nt < 4; ++nt)
#pragma unroll
                    for (int r = 0; r < 4; ++r)
                        s[nt][r] = vexp2(s[nt][r]);
#pragma unroll
                for (int nt = 0; nt < 4; ++nt) {
                    pa[nt * 2]     = cvt_pk_bf16(s[nt][0], s[nt][1]);
                    pa[nt * 2 + 1] = cvt_pk_bf16(s[nt][2], s[nt][3]);
                }
                la += ((s[0][0] + s[0][1]) + (s[0][2] + s[0][3]))
                    + ((s[1][0] + s[1][1]) + (s[1][2] + s[1][3]))
                    + ((s[2][0] + s[2][1]) + (s[2][2] + s[2][3]))
                    + ((s[3][0] + s[3][1]) + (s[3][2] + s[3][3]));
            }

            // ===== group b: same, kb still live
            {
                f32x4 s[4];
#pragma unroll
                for (int nt = 0; nt < 4; ++nt) {
                    s[nt] = __builtin_amdgcn_mfma_f32_16x16x32_bf16(kb[nt], bqb0, minit, 0, 0, 0);
                    s[nt] = __builtin_amdgcn_mfma_f32_16x16x32_bf16(kb[4 + nt], bqb1, s[nt], 0, 0, 0);
                }
                if (kv + 63 > q0w + 16) {
                    const int thr = q0w + 16 + i - kv;
#pragma unroll
                    for (int nt = 0; nt < 4; ++nt)
#pragma unroll
                        for (int r = 0; r < 4; ++r)
                            if (nt * 16 + g4 + r > thr) s[nt][r] = -INFINITY;
                }
#pragma unroll
                for (int nt = 0; nt < 4; ++nt)
#pragma unroll
                    for (int r = 0; r < 4; ++r)
                        s[nt][r] = vexp2(s[nt][r]);
#pragma unroll
                for (int nt = 0; nt < 4; ++nt) {
                    pb2[nt * 2]     = cvt_pk_bf16(s[nt][0], s[nt][1]);
                    pb2[nt * 2 + 1] = cvt_pk_bf16(s[nt][2], s[nt][3]);
                }
                lb += ((s[0][0] + s[0][1]) + (s[0][2] + s[0][3]))
                    + ((s[1][0] + s[1][1]) + (s[1][2] + s[1][3]))
                    + ((s[2][0] + s[2][1]) + (s[2][2] + s[2][3]))
                    + ((s[3][0] + s[3][1]) + (s[3][2] + s[3][3]));
            }

            // ---- V fragments (kb dead -> registers reused), then PV a & b
            s16x8 vb[8];
#pragma unroll
            for (int kst = 0; kst < 2; ++kst)
#pragma unroll
                for (int nt = 0; nt < 4; ++nt)
                    vb[kst * 4 + nt] = *(const s16x8*)
                        &vs[cur][(nt * 16 + i) * 64 + (((kst * 4 + g) ^ (i & 7)) * 8)];

#pragma unroll
            for (int kst = 0; kst < 2; ++kst) {
                union { unsigned u[4]; s16x8 v; } fa, fb;
                fa.u[0] = pa[4 * kst];      fa.u[1] = pa[4 * kst + 1];
                fa.u[2] = pa[4 * kst + 2];  fa.u[3] = pa[4 * kst + 3];
                fb.u[0] = pb2[4 * kst];     fb.u[1] = pb2[4 * kst + 1];
                fb.u[2] = pb2[4 * kst + 2]; fb.u[3] = pb2[4 * kst + 3];
#pragma unroll
                for (int nt = 0; nt < 4; ++nt) {
                    oa[nt] = __builtin_amdgcn_mfma_f32_16x16x32_bf16(vb[kst * 4 + nt], fa.v, oa[nt], 0, 0, 0);
                    ob[nt] = __builtin_amdgcn_mfma_f32_16x16x32_bf16(vb[kst * 4 + nt], fb.v, ob[nt], 0, 0, 0);
                }
            }
        }

        // ---- counted-vmcnt barrier: this iteration's 4 loads stay in flight
        if (issue) asm volatile("s_waitcnt vmcnt(4)\n\ts_barrier" ::: "memory");
        else       asm volatile("s_waitcnt vmcnt(0)\n\ts_barrier" ::: "memory");
    }

    // ---- reduce l across the 4 lane-groups (once), write bf16 partials
    la += __shfl_xor(la, 16);  la += __shfl_xor(la, 32);
    lb += __shfl_xor(lb, 16);  lb += __shfl_xor(lb, 32);
    unsigned short* opA = Opb + ((size_t)bid * 128 + w * 32 + i) * 64;
    unsigned short* opB = opA + 16 * 64;
#pragma unroll
    for (int nt = 0; nt < 4; ++nt) {
        u32x2 pk;
        pk[0] = cvt_pk_bf16(oa[nt][0], oa[nt][1]);
        pk[1] = cvt_pk_bf16(oa[nt][2], oa[nt][3]);
        *(u32x2*)(opA + nt * 16 + g4) = pk;
        pk[0] = cvt_pk_bf16(ob[nt][0], ob[nt][1]);
        pk[1] = cvt_pk_bf16(ob[nt][2], ob[nt][3]);
        *(u32x2*)(opB + nt * 16 + g4) = pk;
    }
    if (g == 0) {
        lpart[(size_t)bid * 128 + w * 32 + i]      = la;
        lpart[(size_t)bid * 128 + w * 32 + 16 + i] = lb;
    }
}

// ---------------------------------------------------------------------------
// Kernel 4: linear merge of the 8 KV splits (fixed base -> no max logic).
// 1024 blocks x 256 thr; thread -> one f32x4 of one output row.
// ---------------------------------------------------------------------------
__global__ __launch_bounds__(256) void merge8(
    const unsigned short* __restrict__ Opb, const float* __restrict__ lpart,
    float* __restrict__ out) {
    const int idx = blockIdx.x * 256 + threadIdx.x;     // 262144 = 16384 x 16
    const int row = idx >> 4, c4 = (idx & 15) * 4;
    const int b = row >> 12, q = row & 4095;
    const int qt = q >> 7, r = q & 127;
    const int qti = 31 - qt;

    float L = 0.f;
    f32x4 o = (f32x4){0.f, 0.f, 0.f, 0.f};
#pragma unroll
    for (int sp = 0; sp < 8; ++sp) {
        const int bidp = qti * 32 + sp * 4 + b;
        L += lpart[(size_t)bidp * 128 + r];
        union { unsigned long long d; unsigned short s[4]; } v;
        v.d = *(const unsigned long long*)&Opb[((size_t)bidp * 128 + r) * 64 + c4];
#pragma unroll
        for (int k = 0; k < 4; ++k) {
            union { unsigned u; float f; } cv;
            cv.u = (unsigned)v.s[k] << 16;
            o[k] += cv.f;
        }
    }
    const float inv = 1.0f / L;
    f32x4 res = (f32x4){o[0] * inv, o[1] * inv, o[2] * inv, o[3] * inv};
    *(f32x4*)&out[(size_t)row * 64 + c4] = res;
}

// ---------------------------------------------------------------------------
extern "C" void kernel_launch(void* const* d_in, const int* in_sizes, int n_in,
                              void* d_out, int out_size, void* d_ws, size_t ws_size,
                              hipStream_t stream) {
    (void)in_sizes; (void)n_in; (void)out_size; (void)ws_size;
    const float* x  = (const float*)d_in[0];
    const float* Wq = (const float*)d_in[1];
    const float* Wk = (const float*)d_in[2];
    const float* Wv = (const float*)d_in[3];
    float* out = (float*)d_out;

    char* ws = (char*)d_ws;
    unsigned short* Q  = (unsigned short*)(ws);
    unsigned short* K  = (unsigned short*)(ws + (size_t)1 * M * H * 2);
    unsigned short* VT = (unsigned short*)(ws + (size_t)3 * M * H * 2);
    unsigned short* Wt = (unsigned short*)(ws + (size_t)4 * M * H * 2);     // 384 KB
    unsigned short* Opb = (unsigned short*)(ws + (size_t)4 * M * H * 2 + 512 * 1024);  // 16.8 MB
    float* lpart = (float*)(ws + (size_t)4 * M * H * 2 + 512 * 1024
                            + (size_t)1024 * 128 * 64 * 2);                 // 512 KB
    // total workspace ~26 MB

    prep_w<<<192, 256, 0, stream>>>(Wq, Wk, Wv, Wt);
    qkv_proj<<<M / 32, 512, 0, stream>>>(x, Wt, Q, K, VT);
    attn<<<1024, 256, 0, stream>>>(Q, K, VT, Opb, lpart);
    merge8<<<1024, 256, 0, stream>>>(Opb, lpart, out);
}

// Round 17
// 50.269 us; speedup vs baseline: 4.1714x; 1.0099x over previous
//
#include <hip/hip_runtime.h>

// SelfAttentionHead: B=4, T=4096, C=1024, H=64, causal, f32 in/out.
// prep_w -> qkv_proj (LDS dbuf MFMA GEMM; Q pre-scaled; V written DIRECTLY
// in key-permuted VT layout) -> attn (triple-buffered LDS K/V, counted-vmcnt
// barriers, swapped QK^T, fixed-base softmax with raw v_exp_f32, unroll-3
// compile-time buffer indices, l-sum via ones-MFMA, 32 q-rows/wave, 8-way
// KV split) -> merge8 (linear combine, bf16 partials).

typedef short  s16x8 __attribute__((ext_vector_type(8)));
typedef float  f32x4 __attribute__((ext_vector_type(4)));
typedef unsigned u32x2 __attribute__((ext_vector_type(2)));

constexpr int B = 4, T = 4096, C = 1024, H = 64;
constexpr int M = B * T;                    // 16384 tokens
constexpr float LOG2E = 1.44269504088896340736f;
constexpr float QSCALE = 0.125f * LOG2E;    // H^-0.5 * log2(e): s in log2 domain
constexpr float MBASE  = 4.0f * LOG2E;      // fixed softmax base (nat-log 4)

__device__ __forceinline__ unsigned short f2bf(float f) {
    union { float f; unsigned u; } v; v.f = f;
    unsigned r = v.u + 0x7fffu + ((v.u >> 16) & 1u);   // RNE
    return (unsigned short)(r >> 16);
}

__device__ __forceinline__ unsigned cvt_pk_bf16(float lo, float hi) {
    unsigned r;
    asm("v_cvt_pk_bf16_f32 %0, %1, %2" : "=v"(r) : "v"(lo), "v"(hi));
    return r;   // [15:0]=bf16(lo), [31:16]=bf16(hi)
}

__device__ __forceinline__ float vexp2(float x) {    // raw v_exp_f32: 2^x
    float r;
    asm("v_exp_f32 %0, %1" : "=v"(r) : "v"(x));
    return r;
}

__device__ __forceinline__ void gl_lds16(const void* g, void* l) {
    __builtin_amdgcn_global_load_lds(
        (const __attribute__((address_space(1))) unsigned*)g,
        (__attribute__((address_space(3))) unsigned*)l, 16, 0, 0);
}

// ---------------------------------------------------------------------------
// Kernel 1: Wt[n][k] = W_{n/64}[k][n%64] as bf16.
// ---------------------------------------------------------------------------
__global__ void prep_w(const float* __restrict__ Wq, const float* __restrict__ Wk,
                       const float* __restrict__ Wv, unsigned short* __restrict__ Wt) {
    const int n = blockIdx.x;                       // 0..191
    const float* W = (n < 64) ? Wq : (n < 128 ? Wk : Wv);
    const int col = n & 63;
    for (int k = threadIdx.x; k < C; k += blockDim.x)
        Wt[(size_t)n * C + k] = f2bf(W[(size_t)k * H + col]);
}

// ---------------------------------------------------------------------------
// Kernel 2: fused QKV projection.  M=16384,K=1024,N=192 bf16 MFMA.
// 512 blocks x 512 thr (8 waves) share one BM=32 x BN=192 x BK=64
// double-buffered LDS tile.  B staged with global_load_lds (linear dest,
// pre-swizzled source); A reg-staged f32->bf16.  Q pre-scaled by QSCALE.
// V written directly into key-permuted transposed layout VT[b][h][pos].
// ---------------------------------------------------------------------------
__global__ __launch_bounds__(512) void qkv_proj(
    const float* __restrict__ x, const unsigned short* __restrict__ Wt,
    unsigned short* __restrict__ Q, unsigned short* __restrict__ K,
    unsigned short* __restrict__ VT) {
    __shared__ __align__(16) unsigned short ldsA[2][32 * 64];    //  8 KB
    __shared__ __align__(16) unsigned short ldsB[2][192 * 64];   // 48 KB

    const int t = threadIdx.x, lane = t & 63, w = t >> 6;
    const int i = lane & 15, g = lane >> 4;
    const int rowbase = blockIdx.x * 32;
    const int rw = w & 1, nw = w >> 1;              // row-group, N-quarter

    const int arow = t >> 3, aslot = t & 7;
    const float* aga = x + (size_t)(rowbase + arow) * C + ((aslot ^ (arow & 7)) * 8);
    const int awoff = arow * 64 + aslot * 8;
    const bool astage = (t < 256);

    const int brow8 = lane >> 3, bslot = lane & 7;
    const unsigned short* bga[3];
    int bn0[3];
#pragma unroll
    for (int j = 0; j < 3; ++j) {
        bn0[j] = w * 24 + j * 8;
        bga[j] = Wt + (size_t)(bn0[j] + brow8) * C + ((bslot ^ brow8) * 8);
    }

    f32x4 acc[3];
#pragma unroll
    for (int n = 0; n < 3; ++n) acc[n] = (f32x4){0.f, 0.f, 0.f, 0.f};

    {
#pragma unroll
        for (int j = 0; j < 3; ++j)
            gl_lds16(bga[j], &ldsB[0][bn0[j] * 64]);
        if (astage) {
            f32x4 a0 = *(const f32x4*)(aga);
            f32x4 a1 = *(const f32x4*)(aga + 4);
            union { unsigned u[4]; s16x8 v; } av;
            av.u[0] = cvt_pk_bf16(a0[0], a0[1]);
            av.u[1] = cvt_pk_bf16(a0[2], a0[3]);
            av.u[2] = cvt_pk_bf16(a1[0], a1[1]);
            av.u[3] = cvt_pk_bf16(a1[2], a1[3]);
            *(s16x8*)&ldsA[0][awoff] = av.v;
        }
    }
    __syncthreads();

    for (int it = 0; it < 16; ++it) {
        const int cur = it & 1, nxt = cur ^ 1;
        const int kc = (it + 1) * 64;
        f32x4 a0, a1;
        const bool more = (it < 15);
        if (more) {
            if (astage) {
                a0 = *(const f32x4*)(aga + kc);
                a1 = *(const f32x4*)(aga + kc + 4);
            }
#pragma unroll
            for (int j = 0; j < 3; ++j)
                gl_lds16(bga[j] + kc, &ldsB[nxt][bn0[j] * 64]);
        }
#pragma unroll
        for (int kst = 0; kst < 2; ++kst) {
            const int c = kst * 4 + g;
            s16x8 a = *(const s16x8*)&ldsA[cur][(rw * 16 + i) * 64 + ((c ^ (i & 7)) * 8)];
#pragma unroll
            for (int nt = 0; nt < 3; ++nt) {
                int n = nw * 48 + nt * 16 + i;        // n&7 == i&7
                s16x8 b = *(const s16x8*)&ldsB[cur][n * 64 + ((c ^ (i & 7)) * 8)];
                acc[nt] = __builtin_amdgcn_mfma_f32_16x16x32_bf16(a, b, acc[nt], 0, 0, 0);
            }
        }
        if (more && astage) {
            union { unsigned u[4]; s16x8 v; } av;
            av.u[0] = cvt_pk_bf16(a0[0], a0[1]);
            av.u[1] = cvt_pk_bf16(a0[2], a0[3]);
            av.u[2] = cvt_pk_bf16(a1[0], a1[1]);
            av.u[3] = cvt_pk_bf16(a1[2], a1[3]);
            *(s16x8*)&ldsA[nxt][awoff] = av.v;
        }
        __syncthreads();
    }

    // epilogue: D layout col=lane&15, row=4*(lane>>4)+r; per-nt region uniform
#pragma unroll
    for (int nt = 0; nt < 3; ++nt) {
        const int base = nw * 48 + nt * 16;
        const int n = base + i;
        if (base >= 128) {          // V -> direct key-permuted VT store
            const int h = n - 128;
            const int bb = rowbase >> 12, tb = rowbase & 4095;
            u32x2 pk;
            pk[0] = cvt_pk_bf16(acc[nt][0], acc[nt][1]);
            pk[1] = cvt_pk_bf16(acc[nt][2], acc[nt][3]);
            *(u32x2*)(VT + (size_t)(bb * H + h) * T + tb + g * 8 + rw * 4) = pk;
        } else if (base >= 64) {    // K
#pragma unroll
            for (int r = 0; r < 4; ++r)
                K[(size_t)(rowbase + rw * 16 + g * 4 + r) * H + (n - 64)] = f2bf(acc[nt][r]);
        } else {                    // Q (pre-scaled)
#pragma unroll
            for (int r = 0; r < 4; ++r)
                Q[(size_t)(rowbase + rw * 16 + g * 4 + r) * H + n] = f2bf(acc[nt][r] * QSCALE);
        }
    }
}

// ---------------------------------------------------------------------------
// attn tile body, CUR = compile-time LDS buffer index (0/1/2).
// ---------------------------------------------------------------------------
template<int CUR>
__device__ __forceinline__ void attn_tile(
    int n, int nTiles, int sp, int q0w, int i, int g, int g4, int w,
    int r8, int sl, int sx,
    const unsigned short* Kb, const unsigned short* Vb,
    unsigned short (&ks)[3][64 * 64], unsigned short (&vs)[3][64 * 64],
    const s16x8& bqa0, const s16x8& bqa1, const s16x8& bqb0, const s16x8& bqb1,
    const s16x8& ones, const f32x4& minit,
    f32x4 (&oa)[4], f32x4 (&ob)[4], f32x4& al, f32x4& bl) {
    constexpr int NXT = (CUR + 2) % 3;
    const int kv = (sp + n * 8) * 64;
    const bool issue = (n + 2 < nTiles);

    // ---- stage tile+16 into buffer NXT (async; 2 tiles of latency cover)
    if (issue) {
        const int kvn = kv + 1024;
#pragma unroll
        for (int j = 0; j < 2; ++j) {
            const int row = (w + j * 4) * 8 + r8;
            gl_lds16(Kb + (size_t)(kvn + row) * H + sx * 8, &ks[NXT][row * 64 + sl * 8]);
            gl_lds16(Vb + (size_t)row * T + kvn + sx * 8,   &vs[NXT][row * 64 + sl * 8]);
        }
    }

    // ---- skip if both q-groups entirely below the tile
    if (kv <= q0w + 31) {
        // ---- K fragments (shared by both q-groups); CUR offset = immediate
        s16x8 kb[8];
#pragma unroll
        for (int kst = 0; kst < 2; ++kst)
#pragma unroll
            for (int nt = 0; nt < 4; ++nt)
                kb[kst * 4 + nt] = *(const s16x8*)
                    &ks[CUR][(nt * 16 + i) * 64 + (((kst * 4 + g) ^ (i & 7)) * 8)];

        unsigned pa[8], pb2[8];

        // ===== group a: QK^T (C-operand init) -> mask -> exp -> pack
        {
            f32x4 s[4];
#pragma unroll
            for (int nt = 0; nt < 4; ++nt) {
                s[nt] = __builtin_amdgcn_mfma_f32_16x16x32_bf16(kb[nt], bqa0, minit, 0, 0, 0);
                s[nt] = __builtin_amdgcn_mfma_f32_16x16x32_bf16(kb[4 + nt], bqa1, s[nt], 0, 0, 0);
            }
            if (kv + 63 > q0w) {
                const int thr = q0w + i - kv;
#pragma unroll
                for (int nt = 0; nt < 4; ++nt)
#pragma unroll
                    for (int r = 0; r < 4; ++r)
                        if (nt * 16 + g4 + r > thr) s[nt][r] = -INFINITY;
            }
#pragma unroll
            for (int nt = 0; nt < 4; ++nt)
#pragma unroll
                for (int r = 0; r < 4; ++r)
                    s[nt][r] = vexp2(s[nt][r]);
#pragma unroll
            for (int nt = 0; nt < 4; ++nt) {
                pa[nt * 2]     = cvt_pk_bf16(s[nt][0], s[nt][1]);
                pa[nt * 2 + 1] = cvt_pk_bf16(s[nt][2], s[nt][3]);
            }
        }

        // ===== group b: same, kb still live
        {
            f32x4 s[4];
#pragma unroll
            for (int nt = 0; nt < 4; ++nt) {
                s[nt] = __builtin_amdgcn_mfma_f32_16x16x32_bf16(kb[nt], bqb0, minit, 0, 0, 0);
                s[nt] = __builtin_amdgcn_mfma_f32_16x16x32_bf16(kb[4 + nt], bqb1, s[nt], 0, 0, 0);
            }
            if (kv + 63 > q0w + 16) {
                const int thr = q0w + 16 + i - kv;
#pragma unroll
                for (int nt = 0; nt < 4; ++nt)
#pragma unroll
                    for (int r = 0; r < 4; ++r)
                        if (nt * 16 + g4 + r > thr) s[nt][r] = -INFINITY;
            }
#pragma unroll
            for (int nt = 0; nt < 4; ++nt)
#pragma unroll
                for (int r = 0; r < 4; ++r)
                    s[nt][r] = vexp2(s[nt][r]);
#pragma unroll
            for (int nt = 0; nt < 4; ++nt) {
                pb2[nt * 2]     = cvt_pk_bf16(s[nt][0], s[nt][1]);
                pb2[nt * 2 + 1] = cvt_pk_bf16(s[nt][2], s[nt][3]);
            }
        }

        // ---- V fragments (kb dead -> registers reused), then PV a & b
        s16x8 vb[8];
#pragma unroll
        for (int kst = 0; kst < 2; ++kst)
#pragma unroll
            for (int nt = 0; nt < 4; ++nt)
                vb[kst * 4 + nt] = *(const s16x8*)
                    &vs[CUR][(nt * 16 + i) * 64 + (((kst * 4 + g) ^ (i & 7)) * 8)];

#pragma unroll
        for (int kst = 0; kst < 2; ++kst) {
            union { unsigned u[4]; s16x8 v; } fa, fb;
            fa.u[0] = pa[4 * kst];      fa.u[1] = pa[4 * kst + 1];
            fa.u[2] = pa[4 * kst + 2];  fa.u[3] = pa[4 * kst + 3];
            fb.u[0] = pb2[4 * kst];     fb.u[1] = pb2[4 * kst + 1];
            fb.u[2] = pb2[4 * kst + 2]; fb.u[3] = pb2[4 * kst + 3];
#pragma unroll
            for (int nt = 0; nt < 4; ++nt) {
                oa[nt] = __builtin_amdgcn_mfma_f32_16x16x32_bf16(vb[kst * 4 + nt], fa.v, oa[nt], 0, 0, 0);
                ob[nt] = __builtin_amdgcn_mfma_f32_16x16x32_bf16(vb[kst * 4 + nt], fb.v, ob[nt], 0, 0, 0);
            }
            // l-sum on the MFMA pipe: A=ones -> every row = sum_k P[k][q]
            al = __builtin_amdgcn_mfma_f32_16x16x32_bf16(ones, fa.v, al, 0, 0, 0);
            bl = __builtin_amdgcn_mfma_f32_16x16x32_bf16(ones, fb.v, bl, 0, 0, 0);
        }
    }

    // ---- counted-vmcnt barrier: this iteration's 4 loads stay in flight
    if (issue) asm volatile("s_waitcnt vmcnt(4)\n\ts_barrier" ::: "memory");
    else       asm volatile("s_waitcnt vmcnt(0)\n\ts_barrier" ::: "memory");
}

// ---------------------------------------------------------------------------
// Kernel 3: causal flash attention.  Triple-buffered LDS K/V (compile-time
// buffer indices via unroll-3), counted s_waitcnt vmcnt(4) barriers.
// 1024 blocks x 256 thr (4 waves), 32 q-rows/wave.  bid = qti*32 + sp*4 + b.
// Fixed-base softmax (raw v_exp_f32); l computed on the MFMA pipe via an
// all-ones A-fragment (no VALU adds, no end shuffles).  bf16 O partials.
// ---------------------------------------------------------------------------
__global__ __launch_bounds__(256) void attn(
    const unsigned short* __restrict__ Qg, const unsigned short* __restrict__ Kg,
    const unsigned short* __restrict__ VTg,
    unsigned short* __restrict__ Opb, float* __restrict__ lpart) {
    __shared__ __align__(16) unsigned short ks[3][64 * 64];   // 3 x 8 KB
    __shared__ __align__(16) unsigned short vs[3][64 * 64];   // 3 x 8 KB

    const int t = threadIdx.x, lane = t & 63, w = t >> 6;
    const int bid = blockIdx.x;
    const int b = bid & 3;
    const int sp = (bid >> 2) & 7;                  // KV split 0..7
    const int qt = 31 - (bid >> 5);                 // heavy-first
    const int q0 = qt * 128;
    const int q0w = q0 + w * 32;                    // wave's first q row
    const int i = lane & 15, g = lane >> 4, g4 = g * 4;
    const int nkv = 2 * qt + 2;
    const int nTiles = (sp < nkv) ? ((nkv - sp + 7) >> 3) : 0;

    const unsigned short* Kb = Kg  + (size_t)b * T * H;
    const unsigned short* Vb = VTg + (size_t)b * H * T;

    // staging map: lane -> rows (w+j*4)*8 + (lane>>3), slot lane&7
    const int r8 = lane >> 3, sl = lane & 7, sx = sl ^ r8;

    // Q fragments for both 16-row groups (col=i=q, k=h)
    const unsigned short* QrowA = Qg + (size_t)(b * T + q0w + i) * H;
    s16x8 bqa0 = *(const s16x8*)(QrowA + g * 8);
    s16x8 bqa1 = *(const s16x8*)(QrowA + 32 + g * 8);
    const unsigned short* QrowB = QrowA + 16 * H;
    s16x8 bqb0 = *(const s16x8*)(QrowB + g * 8);
    s16x8 bqb1 = *(const s16x8*)(QrowB + 32 + g * 8);

    const f32x4 minit = (f32x4){-MBASE, -MBASE, -MBASE, -MBASE};
    s16x8 ones;
#pragma unroll
    for (int j = 0; j < 8; ++j) ones[j] = (short)0x3F80;   // bf16 1.0

    f32x4 oa[4], ob[4];
#pragma unroll
    for (int nt = 0; nt < 4; ++nt) {
        oa[nt] = (f32x4){0.f, 0.f, 0.f, 0.f};
        ob[nt] = (f32x4){0.f, 0.f, 0.f, 0.f};
    }
    f32x4 al = (f32x4){0.f, 0.f, 0.f, 0.f};
    f32x4 bl = (f32x4){0.f, 0.f, 0.f, 0.f};

    // ---- prologue: stage tiles sp, sp+8 into buffers 0, 1 (4 gl_lds each)
    if (nTiles > 0) {
        const int kv0 = sp * 64;
#pragma unroll
        for (int j = 0; j < 2; ++j) {
            const int row = (w + j * 4) * 8 + r8;
            gl_lds16(Kb + (size_t)(kv0 + row) * H + sx * 8, &ks[0][row * 64 + sl * 8]);
            gl_lds16(Vb + (size_t)row * T + kv0 + sx * 8,   &vs[0][row * 64 + sl * 8]);
        }
    }
    if (nTiles > 1) {
        const int kv1 = (sp + 8) * 64;
#pragma unroll
        for (int j = 0; j < 2; ++j) {
            const int row = (w + j * 4) * 8 + r8;
            gl_lds16(Kb + (size_t)(kv1 + row) * H + sx * 8, &ks[1][row * 64 + sl * 8]);
            gl_lds16(Vb + (size_t)row * T + kv1 + sx * 8,   &vs[1][row * 64 + sl * 8]);
        }
        asm volatile("s_waitcnt vmcnt(4)\n\ts_barrier" ::: "memory");
    } else {
        asm volatile("s_waitcnt vmcnt(0)\n\ts_barrier" ::: "memory");
    }

    // ---- main loop, unrolled x3 so the LDS buffer index is compile-time
    {
        int n = 0;
        while (n < nTiles) {
            attn_tile<0>(n, nTiles, sp, q0w, i, g, g4, w, r8, sl, sx, Kb, Vb,
                         ks, vs, bqa0, bqa1, bqb0, bqb1, ones, minit, oa, ob, al, bl);
            if (++n >= nTiles) break;
            attn_tile<1>(n, nTiles, sp, q0w, i, g, g4, w, r8, sl, sx, Kb, Vb,
                         ks, vs, bqa0, bqa1, bqb0, bqb1, ones, minit, oa, ob, al, bl);
            if (++n >= nTiles) break;
            attn_tile<2>(n, nTiles, sp, q0w, i, g, g4, w, r8, sl, sx, Kb, Vb,
                         ks, vs, bqa0, bqa1, bqb0, bqb1, ones, minit, oa, ob, al, bl);
            ++n;
        }
    }

    // ---- write bf16 partials; l complete per-lane from the ones-MFMA
    unsigned short* opA = Opb + ((size_t)bid * 128 + w * 32 + i) * 64;
    unsigned short* opB = opA + 16 * 64;
#pragma unroll
    for (int nt = 0; nt < 4; ++nt) {
        u32x2 pk;
        pk[0] = cvt_pk_bf16(oa[nt][0], oa[nt][1]);
        pk[1] = cvt_pk_bf16(oa[nt][2], oa[nt][3]);
        *(u32x2*)(opA + nt * 16 + g4) = pk;
        pk[0] = cvt_pk_bf16(ob[nt][0], ob[nt][1]);
        pk[1] = cvt_pk_bf16(ob[nt][2], ob[nt][3]);
        *(u32x2*)(opB + nt * 16 + g4) = pk;
    }
    if (g == 0) {
        lpart[(size_t)bid * 128 + w * 32 + i]      = al[0];
        lpart[(size_t)bid * 128 + w * 32 + 16 + i] = bl[0];
    }
}

// ---------------------------------------------------------------------------
// Kernel 4: linear merge of the 8 KV splits (fixed base -> no max logic).
// 1024 blocks x 256 thr; thread -> one f32x4 of one output row.
// ---------------------------------------------------------------------------
__global__ __launch_bounds__(256) void merge8(
    const unsigned short* __restrict__ Opb, const float* __restrict__ lpart,
    float* __restrict__ out) {
    const int idx = blockIdx.x * 256 + threadIdx.x;     // 262144 = 16384 x 16
    const int row = idx >> 4, c4 = (idx & 15) * 4;
    const int b = row >> 12, q = row & 4095;
    const int qt = q >> 7, r = q & 127;
    const int qti = 31 - qt;

    float L = 0.f;
    f32x4 o = (f32x4){0.f, 0.f, 0.f, 0.f};
#pragma unroll
    for (int sp = 0; sp < 8; ++sp) {
        const int bidp = qti * 32 + sp * 4 + b;
        L += lpart[(size_t)bidp * 128 + r];
        union { unsigned long long d; unsigned short s[4]; } v;
        v.d = *(const unsigned long long*)&Opb[((size_t)bidp * 128 + r) * 64 + c4];
#pragma unroll
        for (int k = 0; k < 4; ++k) {
            union { unsigned u; float f; } cv;
            cv.u = (unsigned)v.s[k] << 16;
            o[k] += cv.f;
        }
    }
    const float inv = 1.0f / L;
    f32x4 res = (f32x4){o[0] * inv, o[1] * inv, o[2] * inv, o[3] * inv};
    *(f32x4*)&out[(size_t)row * 64 + c4] = res;
}

// ---------------------------------------------------------------------------
extern "C" void kernel_launch(void* const* d_in, const int* in_sizes, int n_in,
                              void* d_out, int out_size, void* d_ws, size_t ws_size,
                              hipStream_t stream) {
    (void)in_sizes; (void)n_in; (void)out_size; (void)ws_size;
    const float* x  = (const float*)d_in[0];
    const float* Wq = (const float*)d_in[1];
    const float* Wk = (const float*)d_in[2];
    const float* Wv = (const float*)d_in[3];
    float* out = (float*)d_out;

    char* ws = (char*)d_ws;
    unsigned short* Q  = (unsigned short*)(ws);
    unsigned short* K  = (unsigned short*)(ws + (size_t)1 * M * H * 2);
    unsigned short* VT = (unsigned short*)(ws + (size_t)3 * M * H * 2);
    unsigned short* Wt = (unsigned short*)(ws + (size_t)4 * M * H * 2);     // 384 KB
    unsigned short* Opb = (unsigned short*)(ws + (size_t)4 * M * H * 2 + 512 * 1024);  // 16.8 MB
    float* lpart = (float*)(ws + (size_t)4 * M * H * 2 + 512 * 1024
                            + (size_t)1024 * 128 * 64 * 2);                 // 512 KB
    // total workspace ~26 MB

    prep_w<<<192, 256, 0, stream>>>(Wq, Wk, Wv, Wt);
    qkv_proj<<<M / 32, 512, 0, stream>>>(x, Wt, Q, K, VT);
    attn<<<1024, 256, 0, stream>>>(Q, K, VT, Opb, lpart);
    merge8<<<1024, 256, 0, stream>>>(Opb, lpart, out);
}

// Round 18
// 48.869 us; speedup vs baseline: 4.2909x; 1.0286x over previous
//
#include <hip/hip_runtime.h>

// SelfAttentionHead: B=4, T=4096, C=1024, H=64, causal, f32 in/out.
// prep_w -> qkv_proj (LDS dbuf MFMA GEMM; Q pre-scaled; V written DIRECTLY
// in key-permuted VT layout) -> attn (512 co-resident blocks x 8 waves x
// 256 q-rows, triple-buffered LDS K/V, counted-vmcnt barriers, swapped QK^T,
// fixed-base softmax, ones-MFMA l-sum, 8-way KV split) -> merge8.

typedef short  s16x8 __attribute__((ext_vector_type(8)));
typedef float  f32x4 __attribute__((ext_vector_type(4)));
typedef unsigned u32x2 __attribute__((ext_vector_type(2)));

constexpr int B = 4, T = 4096, C = 1024, H = 64;
constexpr int M = B * T;                    // 16384 tokens
constexpr float LOG2E = 1.44269504088896340736f;
constexpr float QSCALE = 0.125f * LOG2E;    // H^-0.5 * log2(e): s in log2 domain
constexpr float MBASE  = 4.0f * LOG2E;      // fixed softmax base (nat-log 4)

__device__ __forceinline__ unsigned short f2bf(float f) {
    union { float f; unsigned u; } v; v.f = f;
    unsigned r = v.u + 0x7fffu + ((v.u >> 16) & 1u);   // RNE
    return (unsigned short)(r >> 16);
}

__device__ __forceinline__ unsigned cvt_pk_bf16(float lo, float hi) {
    unsigned r;
    asm("v_cvt_pk_bf16_f32 %0, %1, %2" : "=v"(r) : "v"(lo), "v"(hi));
    return r;   // [15:0]=bf16(lo), [31:16]=bf16(hi)
}

__device__ __forceinline__ float vexp2(float x) {    // raw v_exp_f32: 2^x
    float r;
    asm("v_exp_f32 %0, %1" : "=v"(r) : "v"(x));
    return r;
}

__device__ __forceinline__ void gl_lds16(const void* g, void* l) {
    __builtin_amdgcn_global_load_lds(
        (const __attribute__((address_space(1))) unsigned*)g,
        (__attribute__((address_space(3))) unsigned*)l, 16, 0, 0);
}

// ---------------------------------------------------------------------------
// Kernel 1: Wt[n][k] = W_{n/64}[k][n%64] as bf16.
// ---------------------------------------------------------------------------
__global__ void prep_w(const float* __restrict__ Wq, const float* __restrict__ Wk,
                       const float* __restrict__ Wv, unsigned short* __restrict__ Wt) {
    const int n = blockIdx.x;                       // 0..191
    const float* W = (n < 64) ? Wq : (n < 128 ? Wk : Wv);
    const int col = n & 63;
    for (int k = threadIdx.x; k < C; k += blockDim.x)
        Wt[(size_t)n * C + k] = f2bf(W[(size_t)k * H + col]);
}

// ---------------------------------------------------------------------------
// Kernel 2: fused QKV projection.  M=16384,K=1024,N=192 bf16 MFMA.
// 512 blocks x 512 thr (8 waves) share one BM=32 x BN=192 x BK=64
// double-buffered LDS tile.  B staged with global_load_lds (linear dest,
// pre-swizzled source); A reg-staged f32->bf16.  Q pre-scaled by QSCALE.
// V written directly into key-permuted transposed layout VT[b][h][pos].
// ---------------------------------------------------------------------------
__global__ __launch_bounds__(512) void qkv_proj(
    const float* __restrict__ x, const unsigned short* __restrict__ Wt,
    unsigned short* __restrict__ Q, unsigned short* __restrict__ K,
    unsigned short* __restrict__ VT) {
    __shared__ __align__(16) unsigned short ldsA[2][32 * 64];    //  8 KB
    __shared__ __align__(16) unsigned short ldsB[2][192 * 64];   // 48 KB

    const int t = threadIdx.x, lane = t & 63, w = t >> 6;
    const int i = lane & 15, g = lane >> 4;
    const int rowbase = blockIdx.x * 32;
    const int rw = w & 1, nw = w >> 1;              // row-group, N-quarter

    const int arow = t >> 3, aslot = t & 7;
    const float* aga = x + (size_t)(rowbase + arow) * C + ((aslot ^ (arow & 7)) * 8);
    const int awoff = arow * 64 + aslot * 8;
    const bool astage = (t < 256);

    const int brow8 = lane >> 3, bslot = lane & 7;
    const unsigned short* bga[3];
    int bn0[3];
#pragma unroll
    for (int j = 0; j < 3; ++j) {
        bn0[j] = w * 24 + j * 8;
        bga[j] = Wt + (size_t)(bn0[j] + brow8) * C + ((bslot ^ brow8) * 8);
    }

    f32x4 acc[3];
#pragma unroll
    for (int n = 0; n < 3; ++n) acc[n] = (f32x4){0.f, 0.f, 0.f, 0.f};

    {
#pragma unroll
        for (int j = 0; j < 3; ++j)
            gl_lds16(bga[j], &ldsB[0][bn0[j] * 64]);
        if (astage) {
            f32x4 a0 = *(const f32x4*)(aga);
            f32x4 a1 = *(const f32x4*)(aga + 4);
            union { unsigned u[4]; s16x8 v; } av;
            av.u[0] = cvt_pk_bf16(a0[0], a0[1]);
            av.u[1] = cvt_pk_bf16(a0[2], a0[3]);
            av.u[2] = cvt_pk_bf16(a1[0], a1[1]);
            av.u[3] = cvt_pk_bf16(a1[2], a1[3]);
            *(s16x8*)&ldsA[0][awoff] = av.v;
        }
    }
    __syncthreads();

    for (int it = 0; it < 16; ++it) {
        const int cur = it & 1, nxt = cur ^ 1;
        const int kc = (it + 1) * 64;
        f32x4 a0, a1;
        const bool more = (it < 15);
        if (more) {
            if (astage) {
                a0 = *(const f32x4*)(aga + kc);
                a1 = *(const f32x4*)(aga + kc + 4);
            }
#pragma unroll
            for (int j = 0; j < 3; ++j)
                gl_lds16(bga[j] + kc, &ldsB[nxt][bn0[j] * 64]);
        }
#pragma unroll
        for (int kst = 0; kst < 2; ++kst) {
            const int c = kst * 4 + g;
            s16x8 a = *(const s16x8*)&ldsA[cur][(rw * 16 + i) * 64 + ((c ^ (i & 7)) * 8)];
#pragma unroll
            for (int nt = 0; nt < 3; ++nt) {
                int n = nw * 48 + nt * 16 + i;        // n&7 == i&7
                s16x8 b = *(const s16x8*)&ldsB[cur][n * 64 + ((c ^ (i & 7)) * 8)];
                acc[nt] = __builtin_amdgcn_mfma_f32_16x16x32_bf16(a, b, acc[nt], 0, 0, 0);
            }
        }
        if (more && astage) {
            union { unsigned u[4]; s16x8 v; } av;
            av.u[0] = cvt_pk_bf16(a0[0], a0[1]);
            av.u[1] = cvt_pk_bf16(a0[2], a0[3]);
            av.u[2] = cvt_pk_bf16(a1[0], a1[1]);
            av.u[3] = cvt_pk_bf16(a1[2], a1[3]);
            *(s16x8*)&ldsA[nxt][awoff] = av.v;
        }
        __syncthreads();
    }

    // epilogue: D layout col=lane&15, row=4*(lane>>4)+r; per-nt region uniform
#pragma unroll
    for (int nt = 0; nt < 3; ++nt) {
        const int base = nw * 48 + nt * 16;
        const int n = base + i;
        if (base >= 128) {          // V -> direct key-permuted VT store
            const int h = n - 128;
            const int bb = rowbase >> 12, tb = rowbase & 4095;
            u32x2 pk;
            pk[0] = cvt_pk_bf16(acc[nt][0], acc[nt][1]);
            pk[1] = cvt_pk_bf16(acc[nt][2], acc[nt][3]);
            *(u32x2*)(VT + (size_t)(bb * H + h) * T + tb + g * 8 + rw * 4) = pk;
        } else if (base >= 64) {    // K
#pragma unroll
            for (int r = 0; r < 4; ++r)
                K[(size_t)(rowbase + rw * 16 + g * 4 + r) * H + (n - 64)] = f2bf(acc[nt][r]);
        } else {                    // Q (pre-scaled)
#pragma unroll
            for (int r = 0; r < 4; ++r)
                Q[(size_t)(rowbase + rw * 16 + g * 4 + r) * H + n] = f2bf(acc[nt][r] * QSCALE);
        }
    }
}

// ---------------------------------------------------------------------------
// attn tile body, CUR = compile-time LDS buffer index (0/1/2).
// 512-thread staging: 1 K + 1 V gl_lds per thread per tile.
// ---------------------------------------------------------------------------
template<int CUR>
__device__ __forceinline__ void attn_tile(
    int n, int nTiles, int sp, int q0w, int i, int g, int g4,
    int srow, int sl, int sx,
    const unsigned short* Kb, const unsigned short* Vb,
    unsigned short (&ks)[3][64 * 64], unsigned short (&vs)[3][64 * 64],
    const s16x8& bqa0, const s16x8& bqa1, const s16x8& bqb0, const s16x8& bqb1,
    const s16x8& ones, const f32x4& minit,
    f32x4 (&oa)[4], f32x4 (&ob)[4], f32x4& al, f32x4& bl) {
    constexpr int NXT = (CUR + 2) % 3;
    const int kv = (sp + n * 8) * 64;
    const bool issue = (n + 2 < nTiles);

    // ---- stage tile+16 into buffer NXT (async; 2 tiles of latency cover)
    if (issue) {
        const int kvn = kv + 1024;
        gl_lds16(Kb + (size_t)(kvn + srow) * H + sx * 8, &ks[NXT][srow * 64 + sl * 8]);
        gl_lds16(Vb + (size_t)srow * T + kvn + sx * 8,   &vs[NXT][srow * 64 + sl * 8]);
    }

    // ---- skip if both q-groups entirely below the tile
    if (kv <= q0w + 31) {
        // ---- K fragments (shared by both q-groups); CUR offset = immediate
        s16x8 kb[8];
#pragma unroll
        for (int kst = 0; kst < 2; ++kst)
#pragma unroll
            for (int nt = 0; nt < 4; ++nt)
                kb[kst * 4 + nt] = *(const s16x8*)
                    &ks[CUR][(nt * 16 + i) * 64 + (((kst * 4 + g) ^ (i & 7)) * 8)];

        unsigned pa[8], pb2[8];

        // ===== group a: QK^T (C-operand init) -> mask -> exp -> pack
        {
            f32x4 s[4];
#pragma unroll
            for (int nt = 0; nt < 4; ++nt) {
                s[nt] = __builtin_amdgcn_mfma_f32_16x16x32_bf16(kb[nt], bqa0, minit, 0, 0, 0);
                s[nt] = __builtin_amdgcn_mfma_f32_16x16x32_bf16(kb[4 + nt], bqa1, s[nt], 0, 0, 0);
            }
            if (kv + 63 > q0w) {
                const int thr = q0w + i - kv;
#pragma unroll
                for (int nt = 0; nt < 4; ++nt)
#pragma unroll
                    for (int r = 0; r < 4; ++r)
                        if (nt * 16 + g4 + r > thr) s[nt][r] = -INFINITY;
            }
#pragma unroll
            for (int nt = 0; nt < 4; ++nt)
#pragma unroll
                for (int r = 0; r < 4; ++r)
                    s[nt][r] = vexp2(s[nt][r]);
#pragma unroll
            for (int nt = 0; nt < 4; ++nt) {
                pa[nt * 2]     = cvt_pk_bf16(s[nt][0], s[nt][1]);
                pa[nt * 2 + 1] = cvt_pk_bf16(s[nt][2], s[nt][3]);
            }
        }

        // ===== group b: same, kb still live
        {
            f32x4 s[4];
#pragma unroll
            for (int nt = 0; nt < 4; ++nt) {
                s[nt] = __builtin_amdgcn_mfma_f32_16x16x32_bf16(kb[nt], bqb0, minit, 0, 0, 0);
                s[nt] = __builtin_amdgcn_mfma_f32_16x16x32_bf16(kb[4 + nt], bqb1, s[nt], 0, 0, 0);
            }
            if (kv + 63 > q0w + 16) {
                const int thr = q0w + 16 + i - kv;
#pragma unroll
                for (int nt = 0; nt < 4; ++nt)
#pragma unroll
                    for (int r = 0; r < 4; ++r)
                        if (nt * 16 + g4 + r > thr) s[nt][r] = -INFINITY;
            }
#pragma unroll
            for (int nt = 0; nt < 4; ++nt)
#pragma unroll
                for (int r = 0; r < 4; ++r)
                    s[nt][r] = vexp2(s[nt][r]);
#pragma unroll
            for (int nt = 0; nt < 4; ++nt) {
                pb2[nt * 2]     = cvt_pk_bf16(s[nt][0], s[nt][1]);
                pb2[nt * 2 + 1] = cvt_pk_bf16(s[nt][2], s[nt][3]);
            }
        }

        // ---- V fragments (kb dead -> registers reused), then PV a & b
        s16x8 vb[8];
#pragma unroll
        for (int kst = 0; kst < 2; ++kst)
#pragma unroll
            for (int nt = 0; nt < 4; ++nt)
                vb[kst * 4 + nt] = *(const s16x8*)
                    &vs[CUR][(nt * 16 + i) * 64 + (((kst * 4 + g) ^ (i & 7)) * 8)];

#pragma unroll
        for (int kst = 0; kst < 2; ++kst) {
            union { unsigned u[4]; s16x8 v; } fa, fb;
            fa.u[0] = pa[4 * kst];      fa.u[1] = pa[4 * kst + 1];
            fa.u[2] = pa[4 * kst + 2];  fa.u[3] = pa[4 * kst + 3];
            fb.u[0] = pb2[4 * kst];     fb.u[1] = pb2[4 * kst + 1];
            fb.u[2] = pb2[4 * kst + 2]; fb.u[3] = pb2[4 * kst + 3];
#pragma unroll
            for (int nt = 0; nt < 4; ++nt) {
                oa[nt] = __builtin_amdgcn_mfma_f32_16x16x32_bf16(vb[kst * 4 + nt], fa.v, oa[nt], 0, 0, 0);
                ob[nt] = __builtin_amdgcn_mfma_f32_16x16x32_bf16(vb[kst * 4 + nt], fb.v, ob[nt], 0, 0, 0);
            }
            // l-sum on the MFMA pipe: A=ones -> every row = sum_k P[k][q]
            al = __builtin_amdgcn_mfma_f32_16x16x32_bf16(ones, fa.v, al, 0, 0, 0);
            bl = __builtin_amdgcn_mfma_f32_16x16x32_bf16(ones, fb.v, bl, 0, 0, 0);
        }
    }

    // ---- counted-vmcnt barrier: this iteration's 2 loads stay in flight
    if (issue) asm volatile("s_waitcnt vmcnt(2)\n\ts_barrier" ::: "memory");
    else       asm volatile("s_waitcnt vmcnt(0)\n\ts_barrier" ::: "memory");
}

// ---------------------------------------------------------------------------
// Kernel 3: causal flash attention.  512 blocks x 512 thr (8 waves), 256
// q-rows/block, 32 q-rows/wave -- ALL blocks co-resident (2/CU, 48 KB LDS),
// each staged 16 KB K/V tile reused by 8 waves.  bid = qti*32 + sp*4 + b:
// qt = 15-qti, sp = KV split 0..7, b = batch.  Triple-buffered LDS,
// counted vmcnt(2) barriers, fixed-base softmax, ones-MFMA l-sum.
// ---------------------------------------------------------------------------
__global__ __launch_bounds__(512) void attn(
    const unsigned short* __restrict__ Qg, const unsigned short* __restrict__ Kg,
    const unsigned short* __restrict__ VTg,
    unsigned short* __restrict__ Opb, float* __restrict__ lpart) {
    __shared__ __align__(16) unsigned short ks[3][64 * 64];   // 3 x 8 KB
    __shared__ __align__(16) unsigned short vs[3][64 * 64];   // 3 x 8 KB

    const int t = threadIdx.x, lane = t & 63, w = t >> 6;
    const int bid = blockIdx.x;
    const int b = bid & 3;
    const int sp = (bid >> 2) & 7;                  // KV split 0..7
    const int qt = 15 - (bid >> 5);                 // heavy-first (moot: all resident)
    const int q0 = qt * 256;
    const int q0w = q0 + w * 32;                    // wave's first q row
    const int i = lane & 15, g = lane >> 4, g4 = g * 4;
    const int nkv = 4 * qt + 4;
    const int nTiles = (sp < nkv) ? ((nkv - sp + 7) >> 3) : 0;

    const unsigned short* Kb = Kg  + (size_t)b * T * H;
    const unsigned short* Vb = VTg + (size_t)b * H * T;

    // staging map (512 thr): row t>>3 (0..63), slot t&7; src chunk sl^(row&7)
    const int srow = t >> 3, sl = t & 7, sx = sl ^ (srow & 7);

    // Q fragments for both 16-row groups (col=i=q, k=h)
    const unsigned short* QrowA = Qg + (size_t)(b * T + q0w + i) * H;
    s16x8 bqa0 = *(const s16x8*)(QrowA + g * 8);
    s16x8 bqa1 = *(const s16x8*)(QrowA + 32 + g * 8);
    const unsigned short* QrowB = QrowA + 16 * H;
    s16x8 bqb0 = *(const s16x8*)(QrowB + g * 8);
    s16x8 bqb1 = *(const s16x8*)(QrowB + 32 + g * 8);

    const f32x4 minit = (f32x4){-MBASE, -MBASE, -MBASE, -MBASE};
    s16x8 ones;
#pragma unroll
    for (int j = 0; j < 8; ++j) ones[j] = (short)0x3F80;   // bf16 1.0

    f32x4 oa[4], ob[4];
#pragma unroll
    for (int nt = 0; nt < 4; ++nt) {
        oa[nt] = (f32x4){0.f, 0.f, 0.f, 0.f};
        ob[nt] = (f32x4){0.f, 0.f, 0.f, 0.f};
    }
    f32x4 al = (f32x4){0.f, 0.f, 0.f, 0.f};
    f32x4 bl = (f32x4){0.f, 0.f, 0.f, 0.f};

    // ---- prologue: stage tiles sp, sp+8 into buffers 0, 1 (2 gl_lds each)
    if (nTiles > 0) {
        const int kv0 = sp * 64;
        gl_lds16(Kb + (size_t)(kv0 + srow) * H + sx * 8, &ks[0][srow * 64 + sl * 8]);
        gl_lds16(Vb + (size_t)srow * T + kv0 + sx * 8,   &vs[0][srow * 64 + sl * 8]);
    }
    if (nTiles > 1) {
        const int kv1 = (sp + 8) * 64;
        gl_lds16(Kb + (size_t)(kv1 + srow) * H + sx * 8, &ks[1][srow * 64 + sl * 8]);
        gl_lds16(Vb + (size_t)srow * T + kv1 + sx * 8,   &vs[1][srow * 64 + sl * 8]);
        asm volatile("s_waitcnt vmcnt(2)\n\ts_barrier" ::: "memory");
    } else {
        asm volatile("s_waitcnt vmcnt(0)\n\ts_barrier" ::: "memory");
    }

    // ---- main loop, unrolled x3 so the LDS buffer index is compile-time
    {
        int n = 0;
        while (n < nTiles) {
            attn_tile<0>(n, nTiles, sp, q0w, i, g, g4, srow, sl, sx, Kb, Vb,
                         ks, vs, bqa0, bqa1, bqb0, bqb1, ones, minit, oa, ob, al, bl);
            if (++n >= nTiles) break;
            attn_tile<1>(n, nTiles, sp, q0w, i, g, g4, srow, sl, sx, Kb, Vb,
                         ks, vs, bqa0, bqa1, bqb0, bqb1, ones, minit, oa, ob, al, bl);
            if (++n >= nTiles) break;
            attn_tile<2>(n, nTiles, sp, q0w, i, g, g4, srow, sl, sx, Kb, Vb,
                         ks, vs, bqa0, bqa1, bqb0, bqb1, ones, minit, oa, ob, al, bl);
            ++n;
        }
    }

    // ---- write bf16 partials; l complete per-lane from the ones-MFMA
    unsigned short* opA = Opb + ((size_t)bid * 256 + w * 32 + i) * 64;
    unsigned short* opB = opA + 16 * 64;
#pragma unroll
    for (int nt = 0; nt < 4; ++nt) {
        u32x2 pk;
        pk[0] = cvt_pk_bf16(oa[nt][0], oa[nt][1]);
        pk[1] = cvt_pk_bf16(oa[nt][2], oa[nt][3]);
        *(u32x2*)(opA + nt * 16 + g4) = pk;
        pk[0] = cvt_pk_bf16(ob[nt][0], ob[nt][1]);
        pk[1] = cvt_pk_bf16(ob[nt][2], ob[nt][3]);
        *(u32x2*)(opB + nt * 16 + g4) = pk;
    }
    if (g == 0) {
        lpart[(size_t)bid * 256 + w * 32 + i]      = al[0];
        lpart[(size_t)bid * 256 + w * 32 + 16 + i] = bl[0];
    }
}

// ---------------------------------------------------------------------------
// Kernel 4: linear merge of the 8 KV splits (fixed base -> no max logic).
// 1024 blocks x 256 thr; thread -> one f32x4 of one output row.
// ---------------------------------------------------------------------------
__global__ __launch_bounds__(256) void merge8(
    const unsigned short* __restrict__ Opb, const float* __restrict__ lpart,
    float* __restrict__ out) {
    const int idx = blockIdx.x * 256 + threadIdx.x;     // 262144 = 16384 x 16
    const int row = idx >> 4, c4 = (idx & 15) * 4;
    const int b = row >> 12, q = row & 4095;
    const int qt = q >> 8, r = q & 255;
    const int qti = 15 - qt;

    float L = 0.f;
    f32x4 o = (f32x4){0.f, 0.f, 0.f, 0.f};
#pragma unroll
    for (int sp = 0; sp < 8; ++sp) {
        const int bidp = qti * 32 + sp * 4 + b;
        L += lpart[(size_t)bidp * 256 + r];
        union { unsigned long long d; unsigned short s[4]; } v;
        v.d = *(const unsigned long long*)&Opb[((size_t)bidp * 256 + r) * 64 + c4];
#pragma unroll
        for (int k = 0; k < 4; ++k) {
            union { unsigned u; float f; } cv;
            cv.u = (unsigned)v.s[k] << 16;
            o[k] += cv.f;
        }
    }
    const float inv = 1.0f / L;
    f32x4 res = (f32x4){o[0] * inv, o[1] * inv, o[2] * inv, o[3] * inv};
    *(f32x4*)&out[(size_t)row * 64 + c4] = res;
}

// ---------------------------------------------------------------------------
extern "C" void kernel_launch(void* const* d_in, const int* in_sizes, int n_in,
                              void* d_out, int out_size, void* d_ws, size_t ws_size,
                              hipStream_t stream) {
    (void)in_sizes; (void)n_in; (void)out_size; (void)ws_size;
    const float* x  = (const float*)d_in[0];
    const float* Wq = (const float*)d_in[1];
    const float* Wk = (const float*)d_in[2];
    const float* Wv = (const float*)d_in[3];
    float* out = (float*)d_out;

    char* ws = (char*)d_ws;
    unsigned short* Q  = (unsigned short*)(ws);
    unsigned short* K  = (unsigned short*)(ws + (size_t)1 * M * H * 2);
    unsigned short* VT = (unsigned short*)(ws + (size_t)3 * M * H * 2);
    unsigned short* Wt = (unsigned short*)(ws + (size_t)4 * M * H * 2);     // 384 KB
    unsigned short* Opb = (unsigned short*)(ws + (size_t)4 * M * H * 2 + 512 * 1024);  // 16.8 MB
    float* lpart = (float*)(ws + (size_t)4 * M * H * 2 + 512 * 1024
                            + (size_t)512 * 256 * 64 * 2);                  // 512 KB
    // total workspace ~26 MB

    prep_w<<<192, 256, 0, stream>>>(Wq, Wk, Wv, Wt);
    qkv_proj<<<M / 32, 512, 0, stream>>>(x, Wt, Q, K, VT);
    attn<<<512, 512, 0, stream>>>(Q, K, VT, Opb, lpart);
    merge8<<<1024, 256, 0, stream>>>(Opb, lpart, out);
}